// Round 5
// baseline (2713.626 us; speedup 1.0000x reference)
//
#include <hip/hip_runtime.h>
#include <hip/hip_bf16.h>
#include <float.h>
#include <math.h>

#define DEVFN __device__ __forceinline__

// Compiler-only fence: wave64 executes DS ops in order, so intra-wave LDS
// exchange needs no s_barrier; this just stops compiler reordering.
DEVFN void wavefence() { __builtin_amdgcn_wave_barrier(); }

namespace {
constexpr int Bq = 4, Nq = 8192, Cq = 32, Kq = 16;
constexpr int PTS = Bq * Nq;          // 32768 points
constexpr int CH = 8;                  // knn candidate chunks
constexpr int CAND = Nq / CH;          // 1024 candidates per chunk
constexpr double ROWS = 524288.0;      // PTS * Kq

// stat/bnp region bases (each region: [sum|mean x128][sumsq|scale x128])
constexpr int DS_Y = 0, DS_Z = 256, DS_G = 512, DS_H1 = 768, DS_H2 = 1024;

// workspace byte offsets
constexpr size_t OFF_A   = 0;                         // knn_d (16MB) -> reused as g_raw
constexpr size_t OFF_B   = (size_t)16 << 20;          // knn_j (16MB) -> reused as agg
constexpr size_t OFF_IDX = (size_t)32 << 20;          // idx (2MB)
constexpr size_t OFF_DST = (size_t)34 << 20;          // dstat (1280 doubles)
constexpr size_t OFF_BNP = ((size_t)34 << 20) + 16384;  // bnp (1280 floats)
constexpr size_t OFF_H1  = ((size_t)34 << 20) + 32768;  // h1 raw (16MB)
constexpr size_t OFF_H2  = ((size_t)50 << 20) + 32768;  // h2 raw (16MB)
}

// ---------------- KNN: two-phase select-then-collect ----------------
// Hot scan keeps ONLY the 16 smallest distances via a min/max insertion
// network (no indices -> no scratch demotion); re-scans collect indices:
//   2a: all d <  kth (ascending index order)
//   2b: d == kth while cnt<16 (ascending index = stable top_k tie-break)
// Distance recompute is bit-identical (__fmul_rn/__fadd_rn, non-contractable).

#define TOP16_DECL                                                           \
  float e0=FLT_MAX,e1=FLT_MAX,e2=FLT_MAX,e3=FLT_MAX,e4=FLT_MAX,e5=FLT_MAX,  \
        e6=FLT_MAX,e7=FLT_MAX,e8=FLT_MAX,e9=FLT_MAX,e10=FLT_MAX,            \
        e11=FLT_MAX,e12=FLT_MAX,e13=FLT_MAX,e14=FLT_MAX,e15=FLT_MAX;

#define TINS(i) { const float lo = fminf(e##i, u); u = fmaxf(e##i, u); e##i = lo; }
#define TINS_ALL  TINS(0) TINS(1) TINS(2) TINS(3) TINS(4) TINS(5) TINS(6)    \
                  TINS(7) TINS(8) TINS(9) TINS(10) TINS(11) TINS(12)         \
                  TINS(13) TINS(14) TINS(15)

DEVFN float distf(const float4 c, const float qx, const float qy, const float qz) {
  const float dx = qx - c.x, dy = qy - c.y, dz = qz - c.z;
  return __fadd_rn(__fadd_rn(__fmul_rn(dx, dx), __fmul_rn(dy, dy)), __fmul_rn(dz, dz));
}

__global__ __launch_bounds__(256, 4) void knn_chunk_kernel(const float* __restrict__ xyz,
                                                           float* __restrict__ pd,
                                                           int* __restrict__ pj) {
  const int b = blockIdx.z;
  const int ch = blockIdx.y;
  const int n = blockIdx.x * 256 + threadIdx.x;
  __shared__ __align__(16) float4 tile[CAND];
  const float* xb = xyz + (size_t)b * Nq * 3;
  for (int t = threadIdx.x; t < CAND; t += 256) {
    const int j = ch * CAND + t;
    tile[t] = make_float4(xb[j * 3], xb[j * 3 + 1], xb[j * 3 + 2], 0.f);
  }
  __syncthreads();
  const float qx = xb[n * 3], qy = xb[n * 3 + 1], qz = xb[n * 3 + 2];
  // scan 1: 16 smallest distances (values only)
  TOP16_DECL;
  for (int t = 0; t < CAND; ++t) {
    float u = distf(tile[t], qx, qy, qz);
    TINS_ALL
  }
  const float kth = e15;
  // scan 2a: collect indices with d < kth (ascending index order)
  const size_t base = (((size_t)b * Nq + n) * CH + ch) * Kq;
  int cnt = 0;
  for (int t = 0; t < CAND; ++t) {
    const float d = distf(tile[t], qx, qy, qz);
    if (d < kth) { pd[base + cnt] = d; pj[base + cnt] = ch * CAND + t; ++cnt; }
  }
  // scan 2b: fill remaining slots with ties (d == kth), lowest index first
  for (int t = 0; t < CAND; ++t) {
    const float d = distf(tile[t], qx, qy, qz);
    if (d == kth && cnt < 16) { pd[base + cnt] = d; pj[base + cnt] = ch * CAND + t; ++cnt; }
  }
}

// Merge the 8 partial lists (ascending-index scan -> stable top_k).
__global__ __launch_bounds__(256, 4) void knn_merge_kernel(const float* __restrict__ pd,
                                                           const int* __restrict__ pj,
                                                           int* __restrict__ idxo) {
  const int q = blockIdx.x * 256 + threadIdx.x;
  const float* dp = pd + (size_t)q * CH * Kq;
  const int* jp = pj + (size_t)q * CH * Kq;
  TOP16_DECL;
  for (int t = 0; t < CH * Kq; t += 4) {
    const float4 v = *(const float4*)(dp + t);
    { float u = v.x; TINS_ALL }
    { float u = v.y; TINS_ALL }
    { float u = v.z; TINS_ALL }
    { float u = v.w; TINS_ALL }
  }
  const float kth = e15;
  int* op = idxo + (size_t)q * Kq;
  int cnt = 0;
  for (int t = 0; t < CH * Kq; ++t) {
    const float d = dp[t];
    if (d < kth) { op[cnt] = jp[t]; ++cnt; }
  }
  for (int t = 0; t < CH * Kq; ++t) {
    const float d = dp[t];
    if (d == kth && cnt < 16) { op[cnt] = jp[t]; ++cnt; }
  }
}

// ---------------- enc builder (one wave, one point; wave-private LDS) -------
// enc row layout: [rel.x rel.y rel.z dist f0..f31] padded to 40 floats.
DEVFN void build_enc(const float* __restrict__ xb, const float* __restrict__ fb,
                     const int* __restrict__ idxp, int n, int lane, float* enc) {
  const int k = lane >> 2, sub = lane & 3;
  const int j = idxp[k];
  const float* fr = fb + (size_t)j * Cq;
  float* er = enc + k * 40;
  const float4 f0 = *(const float4*)(fr + sub * 8);
  const float4 f1 = *(const float4*)(fr + sub * 8 + 4);
  *(float4*)(er + 4 + sub * 8) = f0;
  *(float4*)(er + 4 + sub * 8 + 4) = f1;
  if (sub == 0) {
    const float cx = xb[n * 3], cy = xb[n * 3 + 1], cz = xb[n * 3 + 2];
    const float rx = xb[j * 3] - cx, ry = xb[j * 3 + 1] - cy, rz = xb[j * 3 + 2] - cz;
    const float ss = rx * rx + ry * ry + rz * rz;
    er[0] = rx; er[1] = ry; er[2] = rz;
    er[3] = sqrtf(fmaxf(ss, 1e-12f));
  }
}

// dot(enc_row[0..35], wreg) with wave-uniform b128 LDS reads
DEVFN float dot36(const float* __restrict__ er, const float* __restrict__ wreg) {
  float acc = 0.f;
#pragma unroll
  for (int c4 = 0; c4 < 9; ++c4) {
    const float4 ev = *(const float4*)(er + c4 * 4);
    acc += ev.x * wreg[c4 * 4 + 0];
    acc += ev.y * wreg[c4 * 4 + 1];
    acc += ev.z * wreg[c4 * 4 + 2];
    acc += ev.w * wreg[c4 * 4 + 3];
  }
  return acc;
}

// dot(x_row[0..63], sreg) with wave-uniform b128 LDS reads
DEVFN float dot64(const float* __restrict__ xr, const float* __restrict__ sreg) {
  float acc = 0.f;
#pragma unroll
  for (int c4 = 0; c4 < 16; ++c4) {
    const float4 xv = *(const float4*)(xr + c4 * 4);
    acc += xv.x * sreg[c4 * 4 + 0];
    acc += xv.y * sreg[c4 * 4 + 1];
    acc += xv.z * sreg[c4 * 4 + 2];
    acc += xv.w * sreg[c4 * 4 + 3];
  }
  return acc;
}

// ---------------- pass1: y = enc @ w_lse^T, accumulate mean/var stats -------
// No block barriers in the loop: each wave owns encS[wv]; intra-wave LDS
// exchange is ordered by HW (round-4 profile: VALUBusy 16%, occupancy 15% --
// waves were parked at block barriers waiting on the slowest gather).
__global__ __launch_bounds__(256) void pass1_kernel(const float* __restrict__ xyz,
                                                    const float* __restrict__ features,
                                                    const int* __restrict__ idx,
                                                    const float* __restrict__ wl1,
                                                    const float* __restrict__ wl2,
                                                    double* __restrict__ dstat) {
  const int br = blockIdx.y;
  const float* W = br ? wl2 : wl1;
  __shared__ __align__(16) float encS[4][16 * 40];
  const int lane = threadIdx.x & 63, wv = threadIdx.x >> 6;
  float* enc = encS[wv];
  float wreg[36];
#pragma unroll
  for (int c = 0; c < 36; ++c) wreg[c] = W[lane * 36 + c];
  float s1 = 0.f, s2 = 0.f;
  const int wid = blockIdx.x * 4 + wv, nw = gridDim.x * 4;
  for (int p = wid; p < PTS; p += nw) {
    const int b = p >> 13, n = p & (Nq - 1);
    build_enc(xyz + (size_t)b * Nq * 3, features + (size_t)b * Nq * Cq,
              idx + (size_t)p * Kq, n, lane, enc);
    wavefence();
#pragma unroll
    for (int k = 0; k < 16; ++k) {
      const float acc = dot36(enc + k * 40, wreg);
      s1 += acc; s2 += acc * acc;
    }
    wavefence();
  }
  atomicAdd(&dstat[DS_Y + br * 64 + lane], (double)s1);
  atomicAdd(&dstat[DS_Y + 128 + br * 64 + lane], (double)s2);
}

// ---------------- generic BN stat finalize: mean + rsqrt(var+eps) ----------
__global__ void bn_finalize_kernel(const double* __restrict__ dstat, float* __restrict__ bnp,
                                   int base, double invc) {
  const int t = threadIdx.x;  // 128 threads
  const double m = dstat[base + t] * invc;
  const double v = dstat[base + 128 + t] * invc - m * m;
  bnp[base + t] = (float)m;
  bnp[base + 128 + t] = (float)(1.0 / sqrt(v + 1e-5));
}

// ---------------- passA: x = relu(bn(y)); z = x @ sw1^T; z stats -----------
__global__ __launch_bounds__(256) void passA_kernel(const float* __restrict__ xyz,
                                                    const float* __restrict__ features,
                                                    const int* __restrict__ idx,
                                                    const float* __restrict__ wl1,
                                                    const float* __restrict__ wl2,
                                                    const float* __restrict__ s1a,
                                                    const float* __restrict__ s1b,
                                                    const float* __restrict__ bnp,
                                                    double* __restrict__ dstat) {
  const int br = blockIdx.y;
  const float* W = br ? wl2 : wl1;
  const float* S1 = br ? s1b : s1a;
  __shared__ __align__(16) float encS[4][16 * 40];
  __shared__ __align__(16) float xS[4][16 * 68];
  const int lane = threadIdx.x & 63, wv = threadIdx.x >> 6;
  float* enc = encS[wv];
  float* xL = xS[wv];
  float wreg[36];
#pragma unroll
  for (int c = 0; c < 36; ++c) wreg[c] = W[lane * 36 + c];
  float sreg[64];
#pragma unroll
  for (int c = 0; c < 64; ++c) sreg[c] = S1[lane * 64 + c];
  const float ym = bnp[DS_Y + br * 64 + lane];
  const float ys = bnp[DS_Y + 128 + br * 64 + lane];
  float zs1 = 0.f, zs2 = 0.f;
  const int wid = blockIdx.x * 4 + wv, nw = gridDim.x * 4;
  for (int p = wid; p < PTS; p += nw) {
    const int b = p >> 13, n = p & (Nq - 1);
    build_enc(xyz + (size_t)b * Nq * 3, features + (size_t)b * Nq * Cq,
              idx + (size_t)p * Kq, n, lane, enc);
    wavefence();
#pragma unroll
    for (int k = 0; k < 16; ++k) {
      float xv = (dot36(enc + k * 40, wreg) - ym) * ys;
      xv = xv > 0.f ? xv : 0.f;
      xL[k * 68 + lane] = xv;
    }
    wavefence();
#pragma unroll
    for (int k = 0; k < 16; ++k) {
      const float acc = dot64(xL + k * 68, sreg);
      zs1 += acc; zs2 += acc * acc;
    }
    wavefence();
  }
  atomicAdd(&dstat[DS_Z + br * 64 + lane], (double)zs1);
  atomicAdd(&dstat[DS_Z + 128 + br * 64 + lane], (double)zs2);
}

// ---------------- passB: full branch -> g = feat @ mw^T raw; g stats -------
__global__ __launch_bounds__(256) void passB_kernel(const float* __restrict__ xyz,
                                                    const float* __restrict__ features,
                                                    const int* __restrict__ idx,
                                                    const float* __restrict__ wl1,
                                                    const float* __restrict__ wl2,
                                                    const float* __restrict__ s1a,
                                                    const float* __restrict__ s1b,
                                                    const float* __restrict__ s2a,
                                                    const float* __restrict__ s2b,
                                                    const float* __restrict__ sba,
                                                    const float* __restrict__ sbb,
                                                    const float* __restrict__ mwa,
                                                    const float* __restrict__ mwb,
                                                    const float* __restrict__ bnp,
                                                    double* __restrict__ dstat,
                                                    float* __restrict__ graw) {
  const int br = blockIdx.y;
  const float* W = br ? wl2 : wl1;
  const float* S1 = br ? s1b : s1a;
  const float* S2 = br ? s2b : s2a;
  const float* SB = br ? sbb : sba;
  const float* MW = br ? mwb : mwa;
  __shared__ __align__(16) float mwl[64 * 65];
  __shared__ __align__(16) float encS[4][16 * 40];
  __shared__ __align__(16) float xS[4][16 * 68];
  __shared__ __align__(16) float featL[4][64];
  for (int t = threadIdx.x; t < 64 * 64; t += 256) mwl[(t >> 6) * 65 + (t & 63)] = MW[t];
  __syncthreads();  // one-time weight staging only
  const int lane = threadIdx.x & 63, wv = threadIdx.x >> 6;
  float* enc = encS[wv];
  float* xL = xS[wv];
  float wreg[36];
#pragma unroll
  for (int c = 0; c < 36; ++c) wreg[c] = W[lane * 36 + c];
  float sreg[64];
#pragma unroll
  for (int c = 0; c < 64; ++c) sreg[c] = S1[lane * 64 + c];
  const float ym = bnp[DS_Y + br * 64 + lane];
  const float ys = bnp[DS_Y + 128 + br * 64 + lane];
  const float zm = bnp[DS_Z + br * 64 + lane];
  const float zs = bnp[DS_Z + 128 + br * 64 + lane];
  const float sw2r = S2[lane];
  const float sb2v = SB[0];
  float gs1 = 0.f, gs2 = 0.f;
  const int wid = blockIdx.x * 4 + wv, nw = gridDim.x * 4;
  for (int p = wid; p < PTS; p += nw) {
    const int b = p >> 13, n = p & (Nq - 1);
    build_enc(xyz + (size_t)b * Nq * 3, features + (size_t)b * Nq * Cq,
              idx + (size_t)p * Kq, n, lane, enc);
    wavefence();
    float xr[16];
#pragma unroll
    for (int k = 0; k < 16; ++k) {
      float xv = (dot36(enc + k * 40, wreg) - ym) * ys;
      xv = xv > 0.f ? xv : 0.f;
      xr[k] = xv;
      xL[k * 68 + lane] = xv;
    }
    wavefence();
    float pl[16];
#pragma unroll
    for (int k = 0; k < 16; ++k) {
      float h = (dot64(xL + k * 68, sreg) - zm) * zs;
      h = h > 0.f ? h : 0.f;
      pl[k] = h * sw2r;
    }
    // wave-wide sum over 64 lanes (channel dim) for the 16 logits
#pragma unroll
    for (int off = 1; off < 64; off <<= 1) {
#pragma unroll
      for (int k = 0; k < 16; ++k) pl[k] += __shfl_xor(pl[k], off, 64);
    }
    float lg[16];
    float mx = -FLT_MAX;
#pragma unroll
    for (int k = 0; k < 16; ++k) { lg[k] = pl[k] + sb2v; mx = fmaxf(mx, lg[k]); }
    float se = 0.f;
#pragma unroll
    for (int k = 0; k < 16; ++k) { lg[k] = expf(lg[k] - mx); se += lg[k]; }
    const float inv = 1.f / se;
    float f = 0.f;
#pragma unroll
    for (int k = 0; k < 16; ++k) f += xr[k] * (lg[k] * inv);
    featL[wv][lane] = f;
    wavefence();
    float g = 0.f;
#pragma unroll
    for (int c = 0; c < 64; ++c) g += featL[wv][c] * mwl[lane * 65 + c];
    graw[((size_t)br * PTS + p) * 64 + lane] = g;
    gs1 += g; gs2 += g * g;
    wavefence();
  }
  atomicAdd(&dstat[DS_G + br * 64 + lane], (double)gs1);
  atomicAdd(&dstat[DS_G + 128 + br * 64 + lane], (double)gs2);
}

// ---------------- DRB matmul stage (128x128 per-point matvec + stats) ------
__global__ __launch_bounds__(256) void drb_mm_kernel(const float* __restrict__ in,
                                                     const float* __restrict__ wmat,
                                                     const float* __restrict__ bnp,
                                                     double* __restrict__ dstat,
                                                     float* __restrict__ aggout,
                                                     float* __restrict__ rowout,
                                                     int bpIn, int dsOut, int mode) {
  __shared__ __align__(16) float wlds[128 * 129];
  __shared__ __align__(16) float rowS[4][128];
  for (int t = threadIdx.x; t < 128 * 128; t += 256) wlds[(t >> 7) * 129 + (t & 127)] = wmat[t];
  __syncthreads();  // one-time weight staging only
  const int lane = threadIdx.x & 63, wv = threadIdx.x >> 6;
  const float m0 = bnp[bpIn + lane], s0 = bnp[bpIn + 128 + lane];
  const float m1 = bnp[bpIn + 64 + lane], s1 = bnp[bpIn + 128 + 64 + lane];
  float a1s0 = 0.f, a1s1 = 0.f, a2s0 = 0.f, a2s1 = 0.f;
  const int wid = blockIdx.x * 4 + wv, nw = gridDim.x * 4;
  for (int p = wid; p < PTS; p += nw) {
    float v0, v1;
    if (mode == 0) {  // input = g_raw [2][PTS][64]
      v0 = in[(size_t)p * 64 + lane];
      v1 = in[(size_t)PTS * 64 + (size_t)p * 64 + lane];
    } else {          // input = h1 raw [PTS][128]
      v0 = in[(size_t)p * 128 + lane];
      v1 = in[(size_t)p * 128 + 64 + lane];
    }
    v0 = (v0 - m0) * s0; v0 = v0 > 0.f ? v0 : 0.f;
    v1 = (v1 - m1) * s1; v1 = v1 > 0.f ? v1 : 0.f;
    rowS[wv][lane] = v0;
    rowS[wv][64 + lane] = v1;
    if (aggout) {
      aggout[(size_t)p * 128 + lane] = v0;
      aggout[(size_t)p * 128 + 64 + lane] = v1;
    }
    wavefence();
#pragma unroll
    for (int h = 0; h < 2; ++h) {
      const int o = h * 64 + lane;
      float acc = 0.f;
#pragma unroll
      for (int c = 0; c < 128; ++c) acc += rowS[wv][c] * wlds[o * 129 + c];
      rowout[(size_t)p * 128 + o] = acc;
      if (h == 0) { a1s0 += acc; a2s0 += acc * acc; }
      else        { a1s1 += acc; a2s1 += acc * acc; }
    }
    wavefence();
  }
  atomicAdd(&dstat[dsOut + lane], (double)a1s0);
  atomicAdd(&dstat[dsOut + 64 + lane], (double)a1s1);
  atomicAdd(&dstat[dsOut + 128 + lane], (double)a2s0);
  atomicAdd(&dstat[dsOut + 128 + 64 + lane], (double)a2s1);
}

// ---------------- final: out = relu(bn(h2) + agg) ----------------
__global__ __launch_bounds__(256) void final_kernel(const float* __restrict__ h2,
                                                    const float* __restrict__ agg,
                                                    const float* __restrict__ bnp,
                                                    float* __restrict__ out) {
  const size_t e = (size_t)blockIdx.x * 256 + threadIdx.x;
  const int ch = (int)(e & 127);
  const float m = bnp[DS_H2 + ch], s = bnp[DS_H2 + 128 + ch];
  float v = (h2[e] - m) * s + agg[e];
  out[e] = v > 0.f ? v : 0.f;
}

extern "C" void kernel_launch(void* const* d_in, const int* in_sizes, int n_in,
                              void* d_out, int out_size, void* d_ws, size_t ws_size,
                              hipStream_t stream) {
  (void)in_sizes; (void)n_in; (void)out_size; (void)ws_size;
  const float* xyz      = (const float*)d_in[0];
  const float* features = (const float*)d_in[1];
  const float* w_lse1   = (const float*)d_in[2];
  const float* w_lse2   = (const float*)d_in[3];
  const float* ap1_sw1  = (const float*)d_in[4];
  const float* ap1_sw2  = (const float*)d_in[5];
  const float* ap1_sb2  = (const float*)d_in[6];
  const float* ap1_mw   = (const float*)d_in[7];
  const float* ap2_sw1  = (const float*)d_in[8];
  const float* ap2_sw2  = (const float*)d_in[9];
  const float* ap2_sb2  = (const float*)d_in[10];
  const float* ap2_mw   = (const float*)d_in[11];
  const float* drb_w1   = (const float*)d_in[12];
  const float* drb_w2   = (const float*)d_in[13];

  char* ws = (char*)d_ws;
  float*  knn_d = (float*)(ws + OFF_A);
  int*    knn_j = (int*)(ws + OFF_B);
  int*    idx   = (int*)(ws + OFF_IDX);
  double* dstat = (double*)(ws + OFF_DST);
  float*  bnp   = (float*)(ws + OFF_BNP);
  float*  graw  = (float*)(ws + OFF_A);   // reuse after knn done
  float*  agg   = (float*)(ws + OFF_B);   // reuse after knn done
  float*  h1    = (float*)(ws + OFF_H1);
  float*  h2    = (float*)(ws + OFF_H2);
  float*  out   = (float*)d_out;

  hipMemsetAsync(dstat, 0, 1280 * sizeof(double), stream);

  knn_chunk_kernel<<<dim3(Nq / 256, CH, Bq), 256, 0, stream>>>(xyz, knn_d, knn_j);
  knn_merge_kernel<<<dim3(PTS / 256), 256, 0, stream>>>(knn_d, knn_j, idx);

  pass1_kernel<<<dim3(1024, 2), 256, 0, stream>>>(xyz, features, idx, w_lse1, w_lse2, dstat);
  bn_finalize_kernel<<<1, 128, 0, stream>>>(dstat, bnp, DS_Y, 1.0 / ROWS);

  passA_kernel<<<dim3(640, 2), 256, 0, stream>>>(xyz, features, idx, w_lse1, w_lse2,
                                                 ap1_sw1, ap2_sw1, bnp, dstat);
  bn_finalize_kernel<<<1, 128, 0, stream>>>(dstat, bnp, DS_Z, 1.0 / ROWS);

  passB_kernel<<<dim3(384, 2), 256, 0, stream>>>(xyz, features, idx, w_lse1, w_lse2,
                                                 ap1_sw1, ap2_sw1, ap1_sw2, ap2_sw2,
                                                 ap1_sb2, ap2_sb2, ap1_mw, ap2_mw,
                                                 bnp, dstat, graw);
  bn_finalize_kernel<<<1, 128, 0, stream>>>(dstat, bnp, DS_G, 1.0 / PTS);

  drb_mm_kernel<<<dim3(512), 256, 0, stream>>>(graw, drb_w1, bnp, dstat, agg, h1,
                                               DS_G, DS_H1, 0);
  bn_finalize_kernel<<<1, 128, 0, stream>>>(dstat, bnp, DS_H1, 1.0 / PTS);

  drb_mm_kernel<<<dim3(512), 256, 0, stream>>>(h1, drb_w2, bnp, dstat, nullptr, h2,
                                               DS_H1, DS_H2, 1);
  bn_finalize_kernel<<<1, 128, 0, stream>>>(dstat, bnp, DS_H2, 1.0 / PTS);

  final_kernel<<<dim3(PTS * 128 / 256), 256, 0, stream>>>(h2, agg, bnp, out);
}

// Round 7
// 2466.111 us; speedup vs baseline: 1.1004x; 1.1004x over previous
//
#include <hip/hip_runtime.h>
#include <hip/hip_bf16.h>
#include <float.h>
#include <math.h>

#define DEVFN __device__ __forceinline__

// Compiler-only fence: wave64 executes DS ops in order; stops reordering.
DEVFN void wavefence() { __builtin_amdgcn_wave_barrier(); }

namespace {
constexpr int Bq = 4, Nq = 8192, Cq = 32, Kq = 16;
constexpr int PTS = Bq * Nq;          // 32768 points
constexpr int CH = 8;                  // knn candidate chunks
constexpr int CAND = Nq / CH;          // 1024 candidates per chunk
constexpr double ROWS = 524288.0;      // PTS * Kq

// dstat/bnp region bases (each region: [sum|mean x128][sumsq|scale x128])
constexpr int DS_Y = 0, DS_Z = 256, DS_G = 512, DS_H1 = 768, DS_H2 = 1024;

// workspace byte offsets
constexpr size_t OFF_A    = 0;                         // knn_d (16MB) -> reused as g_raw
constexpr size_t OFF_B    = (size_t)16 << 20;          // knn_j (16MB) -> reused as agg
constexpr size_t OFF_IDX  = (size_t)32 << 20;          // idx (2MB)
constexpr size_t OFF_DST  = (size_t)34 << 20;          // dstat (1280 doubles)
constexpr size_t OFF_MST  = ((size_t)34 << 20) + 10240; // mstat (36*37 floats)
constexpr size_t OFF_BNP  = ((size_t)34 << 20) + 16384; // bnp (1280 floats)
constexpr size_t OFF_H1   = ((size_t)34 << 20) + 32768; // h1 raw (16MB)
constexpr size_t OFF_H2   = ((size_t)50 << 20) + 32768; // h2 raw (16MB)
}

// ---------------- KNN: two-phase select-then-collect (unchanged) ------------
#define TOP16_DECL                                                           \
  float e0=FLT_MAX,e1=FLT_MAX,e2=FLT_MAX,e3=FLT_MAX,e4=FLT_MAX,e5=FLT_MAX,  \
        e6=FLT_MAX,e7=FLT_MAX,e8=FLT_MAX,e9=FLT_MAX,e10=FLT_MAX,            \
        e11=FLT_MAX,e12=FLT_MAX,e13=FLT_MAX,e14=FLT_MAX,e15=FLT_MAX;

#define TINS(i) { const float lo = fminf(e##i, u); u = fmaxf(e##i, u); e##i = lo; }
#define TINS_ALL  TINS(0) TINS(1) TINS(2) TINS(3) TINS(4) TINS(5) TINS(6)    \
                  TINS(7) TINS(8) TINS(9) TINS(10) TINS(11) TINS(12)         \
                  TINS(13) TINS(14) TINS(15)

DEVFN float distf(const float4 c, const float qx, const float qy, const float qz) {
  const float dx = qx - c.x, dy = qy - c.y, dz = qz - c.z;
  return __fadd_rn(__fadd_rn(__fmul_rn(dx, dx), __fmul_rn(dy, dy)), __fmul_rn(dz, dz));
}

__global__ __launch_bounds__(256, 4) void knn_chunk_kernel(const float* __restrict__ xyz,
                                                           float* __restrict__ pd,
                                                           int* __restrict__ pj) {
  const int b = blockIdx.z;
  const int ch = blockIdx.y;
  const int n = blockIdx.x * 256 + threadIdx.x;
  __shared__ __align__(16) float4 tile[CAND];
  const float* xb = xyz + (size_t)b * Nq * 3;
  for (int t = threadIdx.x; t < CAND; t += 256) {
    const int j = ch * CAND + t;
    tile[t] = make_float4(xb[j * 3], xb[j * 3 + 1], xb[j * 3 + 2], 0.f);
  }
  __syncthreads();
  const float qx = xb[n * 3], qy = xb[n * 3 + 1], qz = xb[n * 3 + 2];
  TOP16_DECL;
  for (int t = 0; t < CAND; ++t) {
    float u = distf(tile[t], qx, qy, qz);
    TINS_ALL
  }
  const float kth = e15;
  const size_t base = (((size_t)b * Nq + n) * CH + ch) * Kq;
  int cnt = 0;
  for (int t = 0; t < CAND; ++t) {
    const float d = distf(tile[t], qx, qy, qz);
    if (d < kth) { pd[base + cnt] = d; pj[base + cnt] = ch * CAND + t; ++cnt; }
  }
  for (int t = 0; t < CAND; ++t) {
    const float d = distf(tile[t], qx, qy, qz);
    if (d == kth && cnt < 16) { pd[base + cnt] = d; pj[base + cnt] = ch * CAND + t; ++cnt; }
  }
}

__global__ __launch_bounds__(256, 4) void knn_merge_kernel(const float* __restrict__ pd,
                                                           const int* __restrict__ pj,
                                                           int* __restrict__ idxo) {
  const int q = blockIdx.x * 256 + threadIdx.x;
  const float* dp = pd + (size_t)q * CH * Kq;
  const int* jp = pj + (size_t)q * CH * Kq;
  TOP16_DECL;
  for (int t = 0; t < CH * Kq; t += 4) {
    const float4 v = *(const float4*)(dp + t);
    { float u = v.x; TINS_ALL }
    { float u = v.y; TINS_ALL }
    { float u = v.z; TINS_ALL }
    { float u = v.w; TINS_ALL }
  }
  const float kth = e15;
  int* op = idxo + (size_t)q * Kq;
  int cnt = 0;
  for (int t = 0; t < CH * Kq; ++t) {
    const float d = dp[t];
    if (d < kth) { op[cnt] = jp[t]; ++cnt; }
  }
  for (int t = 0; t < CH * Kq; ++t) {
    const float d = dp[t];
    if (d == kth && cnt < 16) { op[cnt] = jp[t]; ++cnt; }
  }
}

// ---------------- gather pipeline pieces ------------------------------------
// 3-stage rotation per wave: idx loaded 2 points ahead, feature/xyz regs 1
// point ahead, commit+compute current. Hides the ~300-900cyc random-gather
// latency behind the previous point's compute.
struct PF { float4 f0, f1; float nx, ny, nz; };

DEVFN PF issue_feat(const float* __restrict__ features, const float* __restrict__ xyz,
                    int p, int j, int sub) {
  const int b = p >> 13;
  const float* fr = features + ((size_t)b * Nq + j) * Cq;
  const float* xb = xyz + ((size_t)b * Nq + j) * 3;
  PF r;
  r.f0 = *(const float4*)(fr + sub * 8);
  r.f1 = *(const float4*)(fr + sub * 8 + 4);
  r.nx = xb[0]; r.ny = xb[1]; r.nz = xb[2];
  return r;
}

DEVFN int issue_idx(const int* __restrict__ idx, int p, int lane) {
  return idx[(size_t)p * Kq + (lane >> 2)];
}

DEVFN float3 issue_query(const float* __restrict__ xyz, int p) {
  const float* q = xyz + (size_t)p * 3;  // [B,N,3] flat: p = b*Nq+n
  return make_float3(q[0], q[1], q[2]);
}

// enc row layout: [rel.x rel.y rel.z dist f0..f31] padded to 40 floats.
DEVFN void commit_enc(float* __restrict__ enc, int lane, const PF& pf,
                      float qx, float qy, float qz) {
  const int k = lane >> 2, sub = lane & 3;
  float* er = enc + k * 40;
  *(float4*)(er + 4 + sub * 8) = pf.f0;
  *(float4*)(er + 4 + sub * 8 + 4) = pf.f1;
  if (sub == 0) {
    const float rx = pf.nx - qx, ry = pf.ny - qy, rz = pf.nz - qz;
    const float ss = rx * rx + ry * ry + rz * rz;
    *(float4*)er = make_float4(rx, ry, rz, sqrtf(fmaxf(ss, 1e-12f)));
  }
}

// dot(enc_row[0..35], wreg) with wave-uniform b128 LDS reads
DEVFN float dot36(const float* __restrict__ er, const float* __restrict__ wreg) {
  float acc = 0.f;
#pragma unroll
  for (int c4 = 0; c4 < 9; ++c4) {
    const float4 ev = *(const float4*)(er + c4 * 4);
    acc += ev.x * wreg[c4 * 4 + 0];
    acc += ev.y * wreg[c4 * 4 + 1];
    acc += ev.z * wreg[c4 * 4 + 2];
    acc += ev.w * wreg[c4 * 4 + 3];
  }
  return acc;
}

// dot(x_row[0..63], sreg) with wave-uniform b128 LDS reads
DEVFN float dot64(const float* __restrict__ xr, const float* __restrict__ sreg) {
  float acc = 0.f;
#pragma unroll
  for (int c4 = 0; c4 < 16; ++c4) {
    const float4 xv = *(const float4*)(xr + c4 * 4);
    acc += xv.x * sreg[c4 * 4 + 0];
    acc += xv.y * sreg[c4 * 4 + 1];
    acc += xv.z * sreg[c4 * 4 + 2];
    acc += xv.w * sreg[c4 * 4 + 3];
  }
  return acc;
}

// pipeline open/close macros: compute body sits BETWEEN them as ordinary code
// (round-6 failure: #pragma not allowed inside macro arguments).
#define GATHER_PROLOGUE                                                      \
  int p = wid;                                                               \
  int jc = issue_idx(idx, p, lane);                                          \
  PF cur = issue_feat(features, xyz, p, jc, lane & 3);                       \
  float3 qc = issue_query(xyz, p);                                           \
  int pn0 = p + nw; if (pn0 >= PTS) pn0 = p;                                 \
  int jn = issue_idx(idx, pn0, lane);                                        \
  float3 qn = issue_query(xyz, pn0);                                         \
  for (; p < PTS; p += nw) {                                                 \
    int pn = p + nw; if (pn >= PTS) pn = p;                                  \
    int pn2 = pn + nw; if (pn2 >= PTS) pn2 = pn;                             \
    PF nxt = issue_feat(features, xyz, pn, jn, lane & 3);                    \
    const int jn2 = issue_idx(idx, pn2, lane);                               \
    const float3 q2 = issue_query(xyz, pn2);                                 \
    commit_enc(enc, lane, cur, qc.x, qc.y, qc.z);                            \
    wavefence();

#define GATHER_EPILOGUE                                                      \
    wavefence();                                                             \
    cur = nxt; qc = qn; qn = q2; jn = jn2;                                   \
  }

// ---------------- encM: M = sum enc^T enc (36x36), v = sum enc --------------
// Replaces pass1: y-stats for BOTH branches follow from branch-independent
// moments (E[y_o] = w_o.v/R, E[y_o^2] = w_o^T M w_o / R).
__global__ __launch_bounds__(256) void encM_kernel(const float* __restrict__ xyz,
                                                   const float* __restrict__ features,
                                                   const int* __restrict__ idx,
                                                   float* __restrict__ mstat) {
  __shared__ __align__(16) float encS[4][16 * 40];
  __shared__ float mred[4][36 * 37];
  const int lane = threadIdx.x & 63, wv = threadIdx.x >> 6;
  float* enc = encS[wv];
  const int li = (lane < 36) ? lane : 0;  // clamp: lanes>=36 compute junk, never stored
  float macc[36];
#pragma unroll
  for (int i = 0; i < 36; ++i) macc[i] = 0.f;
  float vacc = 0.f;
  const int wid = blockIdx.x * 4 + wv, nw = gridDim.x * 4;
  GATHER_PROLOGUE
#pragma unroll
    for (int k = 0; k < 16; ++k) {
      const float* er = enc + k * 40;
      const float ei = er[li];
      vacc += ei;
#pragma unroll
      for (int c4 = 0; c4 < 9; ++c4) {
        const float4 ev = *(const float4*)(er + c4 * 4);
        macc[c4 * 4 + 0] += ei * ev.x;
        macc[c4 * 4 + 1] += ei * ev.y;
        macc[c4 * 4 + 2] += ei * ev.z;
        macc[c4 * 4 + 3] += ei * ev.w;
      }
    }
  GATHER_EPILOGUE
  if (lane < 36) {
#pragma unroll
    for (int j = 0; j < 36; ++j) mred[wv][lane * 37 + j] = macc[j];
    mred[wv][lane * 37 + 36] = vacc;
  }
  __syncthreads();
  for (int t = threadIdx.x; t < 36 * 37; t += 256) {
    const float s = mred[0][t] + mred[1][t] + mred[2][t] + mred[3][t];
    atomicAdd(&mstat[t], s);
  }
}

// y-stat finalize from moments (double precision). thread t = br*64+o.
__global__ void y_finalize_kernel(const float* __restrict__ mstat,
                                  const float* __restrict__ wl1,
                                  const float* __restrict__ wl2,
                                  float* __restrict__ bnp) {
  const int t = threadIdx.x;  // 128
  const int br = t >> 6, o = t & 63;
  const float* W = br ? wl2 : wl1;
  double wrow[36];
  for (int c = 0; c < 36; ++c) wrow[c] = (double)W[o * 36 + c];
  double mean = 0.0, ey2 = 0.0;
  for (int i = 0; i < 36; ++i) {
    mean += wrow[i] * (double)mstat[i * 37 + 36];
    double rowacc = 0.0;
    for (int j = 0; j < 36; ++j) rowacc += wrow[j] * (double)mstat[i * 37 + j];
    ey2 += wrow[i] * rowacc;
  }
  const double invR = 1.0 / ROWS;
  mean *= invR; ey2 *= invR;
  const double var = ey2 - mean * mean;
  bnp[DS_Y + br * 64 + o] = (float)mean;
  bnp[DS_Y + 128 + br * 64 + o] = (float)(1.0 / sqrt(var + 1e-5));
}

// ---------------- generic BN stat finalize: mean + rsqrt(var+eps) -----------
__global__ void bn_finalize_kernel(const double* __restrict__ dstat, float* __restrict__ bnp,
                                   int base, double invc) {
  const int t = threadIdx.x;  // 128 threads
  const double m = dstat[base + t] * invc;
  const double v = dstat[base + 128 + t] * invc - m * m;
  bnp[base + t] = (float)m;
  bnp[base + 128 + t] = (float)(1.0 / sqrt(v + 1e-5));
}

// ---------------- passA: x = relu(bn(y)); z = x @ sw1^T; z stats ------------
__global__ __launch_bounds__(256) void passA_kernel(const float* __restrict__ xyz,
                                                    const float* __restrict__ features,
                                                    const int* __restrict__ idx,
                                                    const float* __restrict__ wl1,
                                                    const float* __restrict__ wl2,
                                                    const float* __restrict__ s1a,
                                                    const float* __restrict__ s1b,
                                                    const float* __restrict__ bnp,
                                                    double* __restrict__ dstat) {
  const int br = blockIdx.y;
  const float* W = br ? wl2 : wl1;
  const float* S1 = br ? s1b : s1a;
  __shared__ __align__(16) float encS[4][16 * 40];
  __shared__ __align__(16) float xS[4][16 * 68];
  const int lane = threadIdx.x & 63, wv = threadIdx.x >> 6;
  float* enc = encS[wv];
  float* xL = xS[wv];
  float wreg[36];
#pragma unroll
  for (int c = 0; c < 36; ++c) wreg[c] = W[lane * 36 + c];
  float sreg[64];
#pragma unroll
  for (int c = 0; c < 64; ++c) sreg[c] = S1[lane * 64 + c];
  const float ym = bnp[DS_Y + br * 64 + lane];
  const float ys = bnp[DS_Y + 128 + br * 64 + lane];
  float zs1 = 0.f, zs2 = 0.f;
  const int wid = blockIdx.x * 4 + wv, nw = gridDim.x * 4;
  GATHER_PROLOGUE
#pragma unroll
    for (int k = 0; k < 16; ++k) {
      float xv = (dot36(enc + k * 40, wreg) - ym) * ys;
      xv = xv > 0.f ? xv : 0.f;
      xL[k * 68 + lane] = xv;
    }
    wavefence();
#pragma unroll
    for (int k = 0; k < 16; ++k) {
      const float acc = dot64(xL + k * 68, sreg);
      zs1 += acc; zs2 += acc * acc;
    }
  GATHER_EPILOGUE
  atomicAdd(&dstat[DS_Z + br * 64 + lane], (double)zs1);
  atomicAdd(&dstat[DS_Z + 128 + br * 64 + lane], (double)zs2);
}

// ---------------- passB: full branch -> g = feat @ mw^T raw; g stats --------
__global__ __launch_bounds__(256) void passB_kernel(const float* __restrict__ xyz,
                                                    const float* __restrict__ features,
                                                    const int* __restrict__ idx,
                                                    const float* __restrict__ wl1,
                                                    const float* __restrict__ wl2,
                                                    const float* __restrict__ s1a,
                                                    const float* __restrict__ s1b,
                                                    const float* __restrict__ s2a,
                                                    const float* __restrict__ s2b,
                                                    const float* __restrict__ sba,
                                                    const float* __restrict__ sbb,
                                                    const float* __restrict__ mwa,
                                                    const float* __restrict__ mwb,
                                                    const float* __restrict__ bnp,
                                                    double* __restrict__ dstat,
                                                    float* __restrict__ graw) {
  const int br = blockIdx.y;
  const float* W = br ? wl2 : wl1;
  const float* S1 = br ? s1b : s1a;
  const float* S2 = br ? s2b : s2a;
  const float* SB = br ? sbb : sba;
  const float* MW = br ? mwb : mwa;
  __shared__ __align__(16) float mwl[64 * 65];
  __shared__ __align__(16) float encS[4][16 * 40];
  __shared__ __align__(16) float xS[4][16 * 68];
  __shared__ __align__(16) float featL[4][64];
  for (int t = threadIdx.x; t < 64 * 64; t += 256) mwl[(t >> 6) * 65 + (t & 63)] = MW[t];
  __syncthreads();  // one-time weight staging only
  const int lane = threadIdx.x & 63, wv = threadIdx.x >> 6;
  float* enc = encS[wv];
  float* xL = xS[wv];
  float wreg[36];
#pragma unroll
  for (int c = 0; c < 36; ++c) wreg[c] = W[lane * 36 + c];
  float sreg[64];
#pragma unroll
  for (int c = 0; c < 64; ++c) sreg[c] = S1[lane * 64 + c];
  const float ym = bnp[DS_Y + br * 64 + lane];
  const float ys = bnp[DS_Y + 128 + br * 64 + lane];
  const float zm = bnp[DS_Z + br * 64 + lane];
  const float zs = bnp[DS_Z + 128 + br * 64 + lane];
  const float sw2r = S2[lane];
  const float sb2v = SB[0];
  float gs1 = 0.f, gs2 = 0.f;
  const int wid = blockIdx.x * 4 + wv, nw = gridDim.x * 4;
  GATHER_PROLOGUE
#pragma unroll
    for (int k = 0; k < 16; ++k) {
      float xv = (dot36(enc + k * 40, wreg) - ym) * ys;
      xv = xv > 0.f ? xv : 0.f;
      xL[k * 68 + lane] = xv;   // x kept in LDS only (xr[16] dropped: VGPR cap)
    }
    wavefence();
    float pl[16];
#pragma unroll
    for (int k = 0; k < 16; ++k) {
      float h = (dot64(xL + k * 68, sreg) - zm) * zs;
      h = h > 0.f ? h : 0.f;
      pl[k] = h * sw2r;
    }
#pragma unroll
    for (int off = 1; off < 64; off <<= 1) {
#pragma unroll
      for (int k = 0; k < 16; ++k) pl[k] += __shfl_xor(pl[k], off, 64);
    }
    float mx = -FLT_MAX;
#pragma unroll
    for (int k = 0; k < 16; ++k) { pl[k] += sb2v; mx = fmaxf(mx, pl[k]); }
    float se = 0.f;
#pragma unroll
    for (int k = 0; k < 16; ++k) { pl[k] = expf(pl[k] - mx); se += pl[k]; }
    const float inv = 1.f / se;
    float f = 0.f;
#pragma unroll
    for (int k = 0; k < 16; ++k) f += xL[k * 68 + lane] * (pl[k] * inv);
    featL[wv][lane] = f;
    wavefence();
    float g = 0.f;
#pragma unroll
    for (int c = 0; c < 64; ++c) g += featL[wv][c] * mwl[lane * 65 + c];
    graw[((size_t)br * PTS + p) * 64 + lane] = g;
    gs1 += g; gs2 += g * g;
  GATHER_EPILOGUE
  atomicAdd(&dstat[DS_G + br * 64 + lane], (double)gs1);
  atomicAdd(&dstat[DS_G + 128 + br * 64 + lane], (double)gs2);
}

// ---------------- DRB matmul stage (128x128 per-point matvec + stats) -------
__global__ __launch_bounds__(256) void drb_mm_kernel(const float* __restrict__ in,
                                                     const float* __restrict__ wmat,
                                                     const float* __restrict__ bnp,
                                                     double* __restrict__ dstat,
                                                     float* __restrict__ aggout,
                                                     float* __restrict__ rowout,
                                                     int bpIn, int dsOut, int mode) {
  __shared__ __align__(16) float wlds[128 * 129];
  __shared__ __align__(16) float rowS[4][128];
  for (int t = threadIdx.x; t < 128 * 128; t += 256) wlds[(t >> 7) * 129 + (t & 127)] = wmat[t];
  __syncthreads();  // one-time weight staging only
  const int lane = threadIdx.x & 63, wv = threadIdx.x >> 6;
  const float m0 = bnp[bpIn + lane], s0 = bnp[bpIn + 128 + lane];
  const float m1 = bnp[bpIn + 64 + lane], s1 = bnp[bpIn + 128 + 64 + lane];
  float a1s0 = 0.f, a1s1 = 0.f, a2s0 = 0.f, a2s1 = 0.f;
  const int wid = blockIdx.x * 4 + wv, nw = gridDim.x * 4;
  for (int p = wid; p < PTS; p += nw) {
    float v0, v1;
    if (mode == 0) {  // input = g_raw [2][PTS][64]
      v0 = in[(size_t)p * 64 + lane];
      v1 = in[(size_t)PTS * 64 + (size_t)p * 64 + lane];
    } else {          // input = h1 raw [PTS][128]
      v0 = in[(size_t)p * 128 + lane];
      v1 = in[(size_t)p * 128 + 64 + lane];
    }
    v0 = (v0 - m0) * s0; v0 = v0 > 0.f ? v0 : 0.f;
    v1 = (v1 - m1) * s1; v1 = v1 > 0.f ? v1 : 0.f;
    rowS[wv][lane] = v0;
    rowS[wv][64 + lane] = v1;
    if (aggout) {
      aggout[(size_t)p * 128 + lane] = v0;
      aggout[(size_t)p * 128 + 64 + lane] = v1;
    }
    wavefence();
#pragma unroll
    for (int h = 0; h < 2; ++h) {
      const int o = h * 64 + lane;
      float acc = 0.f;
#pragma unroll
      for (int c = 0; c < 128; ++c) acc += rowS[wv][c] * wlds[o * 129 + c];
      rowout[(size_t)p * 128 + o] = acc;
      if (h == 0) { a1s0 += acc; a2s0 += acc * acc; }
      else        { a1s1 += acc; a2s1 += acc * acc; }
    }
    wavefence();
  }
  atomicAdd(&dstat[dsOut + lane], (double)a1s0);
  atomicAdd(&dstat[dsOut + 64 + lane], (double)a1s1);
  atomicAdd(&dstat[dsOut + 128 + lane], (double)a2s0);
  atomicAdd(&dstat[dsOut + 128 + 64 + lane], (double)a2s1);
}

// ---------------- final: out = relu(bn(h2) + agg) ---------------------------
__global__ __launch_bounds__(256) void final_kernel(const float* __restrict__ h2,
                                                    const float* __restrict__ agg,
                                                    const float* __restrict__ bnp,
                                                    float* __restrict__ out) {
  const size_t e = (size_t)blockIdx.x * 256 + threadIdx.x;
  const int ch = (int)(e & 127);
  const float m = bnp[DS_H2 + ch], s = bnp[DS_H2 + 128 + ch];
  float v = (h2[e] - m) * s + agg[e];
  out[e] = v > 0.f ? v : 0.f;
}

extern "C" void kernel_launch(void* const* d_in, const int* in_sizes, int n_in,
                              void* d_out, int out_size, void* d_ws, size_t ws_size,
                              hipStream_t stream) {
  (void)in_sizes; (void)n_in; (void)out_size; (void)ws_size;
  const float* xyz      = (const float*)d_in[0];
  const float* features = (const float*)d_in[1];
  const float* w_lse1   = (const float*)d_in[2];
  const float* w_lse2   = (const float*)d_in[3];
  const float* ap1_sw1  = (const float*)d_in[4];
  const float* ap1_sw2  = (const float*)d_in[5];
  const float* ap1_sb2  = (const float*)d_in[6];
  const float* ap1_mw   = (const float*)d_in[7];
  const float* ap2_sw1  = (const float*)d_in[8];
  const float* ap2_sw2  = (const float*)d_in[9];
  const float* ap2_sb2  = (const float*)d_in[10];
  const float* ap2_mw   = (const float*)d_in[11];
  const float* drb_w1   = (const float*)d_in[12];
  const float* drb_w2   = (const float*)d_in[13];

  char* ws = (char*)d_ws;
  float*  knn_d = (float*)(ws + OFF_A);
  int*    knn_j = (int*)(ws + OFF_B);
  int*    idx   = (int*)(ws + OFF_IDX);
  double* dstat = (double*)(ws + OFF_DST);
  float*  mstat = (float*)(ws + OFF_MST);
  float*  bnp   = (float*)(ws + OFF_BNP);
  float*  graw  = (float*)(ws + OFF_A);   // reuse after knn done
  float*  agg   = (float*)(ws + OFF_B);   // reuse after knn done
  float*  h1    = (float*)(ws + OFF_H1);
  float*  h2    = (float*)(ws + OFF_H2);
  float*  out   = (float*)d_out;

  // zero dstat (1280 doubles) + mstat (36*37 floats, contiguous after)
  (void)hipMemsetAsync(dstat, 0, 1280 * sizeof(double) + 36 * 37 * sizeof(float), stream);

  knn_chunk_kernel<<<dim3(Nq / 256, CH, Bq), 256, 0, stream>>>(xyz, knn_d, knn_j);
  knn_merge_kernel<<<dim3(PTS / 256), 256, 0, stream>>>(knn_d, knn_j, idx);

  encM_kernel<<<dim3(512), 256, 0, stream>>>(xyz, features, idx, mstat);
  y_finalize_kernel<<<1, 128, 0, stream>>>(mstat, w_lse1, w_lse2, bnp);

  passA_kernel<<<dim3(640, 2), 256, 0, stream>>>(xyz, features, idx, w_lse1, w_lse2,
                                                 ap1_sw1, ap2_sw1, bnp, dstat);
  bn_finalize_kernel<<<1, 128, 0, stream>>>(dstat, bnp, DS_Z, 1.0 / ROWS);

  passB_kernel<<<dim3(384, 2), 256, 0, stream>>>(xyz, features, idx, w_lse1, w_lse2,
                                                 ap1_sw1, ap2_sw1, ap1_sw2, ap2_sw2,
                                                 ap1_sb2, ap2_sb2, ap1_mw, ap2_mw,
                                                 bnp, dstat, graw);
  bn_finalize_kernel<<<1, 128, 0, stream>>>(dstat, bnp, DS_G, 1.0 / PTS);

  drb_mm_kernel<<<dim3(512), 256, 0, stream>>>(graw, drb_w1, bnp, dstat, agg, h1,
                                               DS_G, DS_H1, 0);
  bn_finalize_kernel<<<1, 128, 0, stream>>>(dstat, bnp, DS_H1, 1.0 / PTS);

  drb_mm_kernel<<<dim3(512), 256, 0, stream>>>(h1, drb_w2, bnp, dstat, nullptr, h2,
                                               DS_H1, DS_H2, 1);
  bn_finalize_kernel<<<1, 128, 0, stream>>>(dstat, bnp, DS_H2, 1.0 / PTS);

  final_kernel<<<dim3(PTS * 128 / 256), 256, 0, stream>>>(h2, agg, bnp, out);
}

// Round 8
// 2066.783 us; speedup vs baseline: 1.3130x; 1.1932x over previous
//
#include <hip/hip_runtime.h>
#include <hip/hip_bf16.h>
#include <float.h>
#include <math.h>

#define DEVFN __device__ __forceinline__

// Compiler-only fence: wave64 executes DS ops in order; stops reordering.
DEVFN void wavefence() { __builtin_amdgcn_wave_barrier(); }

namespace {
constexpr int Bq = 4, Nq = 8192, Cq = 32, Kq = 16;
constexpr int PTS = Bq * Nq;          // 32768 points
constexpr int CH = 8;                  // knn candidate chunks
constexpr int CAND = Nq / CH;          // 1024 candidates per chunk
constexpr double ROWS = 524288.0;      // PTS * Kq

// dstat/bnp region bases (each region: [sum|mean x128][sumsq|scale x128])
constexpr int DS_Y = 0, DS_Z = 256, DS_G = 512, DS_H1 = 768, DS_H2 = 1024;

// workspace byte offsets
constexpr size_t OFF_A    = 0;                         // knn_d (16MB) -> reused as g_raw
constexpr size_t OFF_B    = (size_t)16 << 20;          // knn_j (16MB) -> reused as agg
constexpr size_t OFF_IDX  = (size_t)32 << 20;          // idx (2MB)
constexpr size_t OFF_DST  = (size_t)34 << 20;          // dstat (1280 doubles)
constexpr size_t OFF_MST  = ((size_t)34 << 20) + 10240; // mstat (36*37 floats)
constexpr size_t OFF_BNP  = ((size_t)34 << 20) + 16384; // bnp (1280 floats)
constexpr size_t OFF_H1   = ((size_t)34 << 20) + 32768; // h1 raw (16MB)
constexpr size_t OFF_H2   = ((size_t)50 << 20) + 32768; // h2 raw (16MB)
}

// ---------------- KNN: two-phase select-then-collect (unchanged) ------------
#define TOP16_DECL                                                           \
  float e0=FLT_MAX,e1=FLT_MAX,e2=FLT_MAX,e3=FLT_MAX,e4=FLT_MAX,e5=FLT_MAX,  \
        e6=FLT_MAX,e7=FLT_MAX,e8=FLT_MAX,e9=FLT_MAX,e10=FLT_MAX,            \
        e11=FLT_MAX,e12=FLT_MAX,e13=FLT_MAX,e14=FLT_MAX,e15=FLT_MAX;

#define TINS(i) { const float lo = fminf(e##i, u); u = fmaxf(e##i, u); e##i = lo; }
#define TINS_ALL  TINS(0) TINS(1) TINS(2) TINS(3) TINS(4) TINS(5) TINS(6)    \
                  TINS(7) TINS(8) TINS(9) TINS(10) TINS(11) TINS(12)         \
                  TINS(13) TINS(14) TINS(15)

DEVFN float distf(const float4 c, const float qx, const float qy, const float qz) {
  const float dx = qx - c.x, dy = qy - c.y, dz = qz - c.z;
  return __fadd_rn(__fadd_rn(__fmul_rn(dx, dx), __fmul_rn(dy, dy)), __fmul_rn(dz, dz));
}

__global__ __launch_bounds__(256, 4) void knn_chunk_kernel(const float* __restrict__ xyz,
                                                           float* __restrict__ pd,
                                                           int* __restrict__ pj) {
  const int b = blockIdx.z;
  const int ch = blockIdx.y;
  const int n = blockIdx.x * 256 + threadIdx.x;
  __shared__ __align__(16) float4 tile[CAND];
  const float* xb = xyz + (size_t)b * Nq * 3;
  for (int t = threadIdx.x; t < CAND; t += 256) {
    const int j = ch * CAND + t;
    tile[t] = make_float4(xb[j * 3], xb[j * 3 + 1], xb[j * 3 + 2], 0.f);
  }
  __syncthreads();
  const float qx = xb[n * 3], qy = xb[n * 3 + 1], qz = xb[n * 3 + 2];
  TOP16_DECL;
  for (int t = 0; t < CAND; ++t) {
    float u = distf(tile[t], qx, qy, qz);
    TINS_ALL
  }
  const float kth = e15;
  const size_t base = (((size_t)b * Nq + n) * CH + ch) * Kq;
  int cnt = 0;
  for (int t = 0; t < CAND; ++t) {
    const float d = distf(tile[t], qx, qy, qz);
    if (d < kth) { pd[base + cnt] = d; pj[base + cnt] = ch * CAND + t; ++cnt; }
  }
  for (int t = 0; t < CAND; ++t) {
    const float d = distf(tile[t], qx, qy, qz);
    if (d == kth && cnt < 16) { pd[base + cnt] = d; pj[base + cnt] = ch * CAND + t; ++cnt; }
  }
}

__global__ __launch_bounds__(256, 4) void knn_merge_kernel(const float* __restrict__ pd,
                                                           const int* __restrict__ pj,
                                                           int* __restrict__ idxo) {
  const int q = blockIdx.x * 256 + threadIdx.x;
  const float* dp = pd + (size_t)q * CH * Kq;
  const int* jp = pj + (size_t)q * CH * Kq;
  TOP16_DECL;
  for (int t = 0; t < CH * Kq; t += 4) {
    const float4 v = *(const float4*)(dp + t);
    { float u = v.x; TINS_ALL }
    { float u = v.y; TINS_ALL }
    { float u = v.z; TINS_ALL }
    { float u = v.w; TINS_ALL }
  }
  const float kth = e15;
  int* op = idxo + (size_t)q * Kq;
  int cnt = 0;
  for (int t = 0; t < CH * Kq; ++t) {
    const float d = dp[t];
    if (d < kth) { op[cnt] = jp[t]; ++cnt; }
  }
  for (int t = 0; t < CH * Kq; ++t) {
    const float d = dp[t];
    if (d == kth && cnt < 16) { op[cnt] = jp[t]; ++cnt; }
  }
}

// ---------------- gather pipeline pieces ------------------------------------
struct PF { float4 f0, f1; float nx, ny, nz; };

DEVFN PF issue_feat(const float* __restrict__ features, const float* __restrict__ xyz,
                    int p, int j, int sub) {
  const int b = p >> 13;
  const float* fr = features + ((size_t)b * Nq + j) * Cq;
  const float* xb = xyz + ((size_t)b * Nq + j) * 3;
  PF r;
  r.f0 = *(const float4*)(fr + sub * 8);
  r.f1 = *(const float4*)(fr + sub * 8 + 4);
  r.nx = xb[0]; r.ny = xb[1]; r.nz = xb[2];
  return r;
}

DEVFN int issue_idx(const int* __restrict__ idx, int p, int lane) {
  return idx[(size_t)p * Kq + (lane >> 2)];
}

DEVFN float3 issue_query(const float* __restrict__ xyz, int p) {
  const float* q = xyz + (size_t)p * 3;  // [B,N,3] flat: p = b*Nq+n
  return make_float3(q[0], q[1], q[2]);
}

// enc row layout: [rel.x rel.y rel.z dist f0..f31] padded to 40 floats.
DEVFN void commit_enc(float* __restrict__ enc, int lane, const PF& pf,
                      float qx, float qy, float qz) {
  const int k = lane >> 2, sub = lane & 3;
  float* er = enc + k * 40;
  *(float4*)(er + 4 + sub * 8) = pf.f0;
  *(float4*)(er + 4 + sub * 8 + 4) = pf.f1;
  if (sub == 0) {
    const float rx = pf.nx - qx, ry = pf.ny - qy, rz = pf.nz - qz;
    const float ss = rx * rx + ry * ry + rz * rz;
    *(float4*)er = make_float4(rx, ry, rz, sqrtf(fmaxf(ss, 1e-12f)));
  }
}

// dot(enc_row[0..35], wreg) -- 4 independent accumulators (chain /4)
DEVFN float dot36(const float* __restrict__ er, const float* __restrict__ wreg) {
  float a0 = 0.f, a1 = 0.f, a2 = 0.f, a3 = 0.f;
#pragma unroll
  for (int c4 = 0; c4 < 9; ++c4) {
    const float4 ev = *(const float4*)(er + c4 * 4);
    a0 += ev.x * wreg[c4 * 4 + 0];
    a1 += ev.y * wreg[c4 * 4 + 1];
    a2 += ev.z * wreg[c4 * 4 + 2];
    a3 += ev.w * wreg[c4 * 4 + 3];
  }
  return (a0 + a1) + (a2 + a3);
}

// dot(x_row[0..63], sreg) -- 4 independent accumulators
DEVFN float dot64(const float* __restrict__ xr, const float* __restrict__ sreg) {
  float a0 = 0.f, a1 = 0.f, a2 = 0.f, a3 = 0.f;
#pragma unroll
  for (int c4 = 0; c4 < 16; ++c4) {
    const float4 xv = *(const float4*)(xr + c4 * 4);
    a0 += xv.x * sreg[c4 * 4 + 0];
    a1 += xv.y * sreg[c4 * 4 + 1];
    a2 += xv.z * sreg[c4 * 4 + 2];
    a3 += xv.w * sreg[c4 * 4 + 3];
  }
  return (a0 + a1) + (a2 + a3);
}

// pipeline open/close macros (body sits between them as ordinary code).
#define GATHER_PROLOGUE                                                      \
  int p = wid;                                                               \
  int jc = issue_idx(idx, p, lane);                                          \
  PF cur = issue_feat(features, xyz, p, jc, lane & 3);                       \
  float3 qc = issue_query(xyz, p);                                           \
  int pn0 = p + nw; if (pn0 >= PTS) pn0 = p;                                 \
  int jn = issue_idx(idx, pn0, lane);                                        \
  float3 qn = issue_query(xyz, pn0);                                         \
  for (; p < PTS; p += nw) {                                                 \
    int pn = p + nw; if (pn >= PTS) pn = p;                                  \
    int pn2 = pn + nw; if (pn2 >= PTS) pn2 = pn;                             \
    PF nxt = issue_feat(features, xyz, pn, jn, lane & 3);                    \
    const int jn2 = issue_idx(idx, pn2, lane);                               \
    const float3 q2 = issue_query(xyz, pn2);                                 \
    commit_enc(enc, lane, cur, qc.x, qc.y, qc.z);                            \
    wavefence();

#define GATHER_EPILOGUE                                                      \
    wavefence();                                                             \
    cur = nxt; qc = qn; qn = q2; jn = jn2;                                   \
  }

// ---------------- encM: M = sum enc^T enc (36x36), v = sum enc --------------
__global__ __launch_bounds__(256) void encM_kernel(const float* __restrict__ xyz,
                                                   const float* __restrict__ features,
                                                   const int* __restrict__ idx,
                                                   float* __restrict__ mstat) {
  __shared__ __align__(16) float encS[4][16 * 40];
  __shared__ float mred[4][36 * 37];
  const int lane = threadIdx.x & 63, wv = threadIdx.x >> 6;
  float* enc = encS[wv];
  const int li = (lane < 36) ? lane : 0;  // clamp: lanes>=36 compute junk, never stored
  float macc[36];
#pragma unroll
  for (int i = 0; i < 36; ++i) macc[i] = 0.f;
  float vacc = 0.f;
  const int wid = blockIdx.x * 4 + wv, nw = gridDim.x * 4;
  GATHER_PROLOGUE
#pragma unroll
    for (int k = 0; k < 16; ++k) {
      const float* er = enc + k * 40;
      const float ei = er[li];
      vacc += ei;
#pragma unroll
      for (int c4 = 0; c4 < 9; ++c4) {
        const float4 ev = *(const float4*)(er + c4 * 4);
        macc[c4 * 4 + 0] += ei * ev.x;
        macc[c4 * 4 + 1] += ei * ev.y;
        macc[c4 * 4 + 2] += ei * ev.z;
        macc[c4 * 4 + 3] += ei * ev.w;
      }
    }
  GATHER_EPILOGUE
  if (lane < 36) {
#pragma unroll
    for (int j = 0; j < 36; ++j) mred[wv][lane * 37 + j] = macc[j];
    mred[wv][lane * 37 + 36] = vacc;
  }
  __syncthreads();
  for (int t = threadIdx.x; t < 36 * 37; t += 256) {
    const float s = mred[0][t] + mred[1][t] + mred[2][t] + mred[3][t];
    atomicAdd(&mstat[t], s);
  }
}

// y-stat finalize from moments (double precision). thread t = br*64+o.
__global__ void y_finalize_kernel(const float* __restrict__ mstat,
                                  const float* __restrict__ wl1,
                                  const float* __restrict__ wl2,
                                  float* __restrict__ bnp) {
  const int t = threadIdx.x;  // 128
  const int br = t >> 6, o = t & 63;
  const float* W = br ? wl2 : wl1;
  double wrow[36];
  for (int c = 0; c < 36; ++c) wrow[c] = (double)W[o * 36 + c];
  double mean = 0.0, ey2 = 0.0;
  for (int i = 0; i < 36; ++i) {
    mean += wrow[i] * (double)mstat[i * 37 + 36];
    double rowacc = 0.0;
    for (int j = 0; j < 36; ++j) rowacc += wrow[j] * (double)mstat[i * 37 + j];
    ey2 += wrow[i] * rowacc;
  }
  const double invR = 1.0 / ROWS;
  mean *= invR; ey2 *= invR;
  const double var = ey2 - mean * mean;
  bnp[DS_Y + br * 64 + o] = (float)mean;
  bnp[DS_Y + 128 + br * 64 + o] = (float)(1.0 / sqrt(var + 1e-5));
}

// ---------------- generic BN stat finalize: mean + rsqrt(var+eps) -----------
__global__ void bn_finalize_kernel(const double* __restrict__ dstat, float* __restrict__ bnp,
                                   int base, double invc) {
  const int t = threadIdx.x;  // 128 threads
  const double m = dstat[base + t] * invc;
  const double v = dstat[base + 128 + t] * invc - m * m;
  bnp[base + t] = (float)m;
  bnp[base + 128 + t] = (float)(1.0 / sqrt(v + 1e-5));
}

// ---------------- passA: x = relu(bn(y)); z = x @ sw1^T; z stats ------------
// xS stride 64 (writes 2-way/free, reads broadcast) -> 26KB LDS.
__global__ __launch_bounds__(256) void passA_kernel(const float* __restrict__ xyz,
                                                    const float* __restrict__ features,
                                                    const int* __restrict__ idx,
                                                    const float* __restrict__ wl1,
                                                    const float* __restrict__ wl2,
                                                    const float* __restrict__ s1a,
                                                    const float* __restrict__ s1b,
                                                    const float* __restrict__ bnp,
                                                    double* __restrict__ dstat) {
  const int br = blockIdx.y;
  const float* W = br ? wl2 : wl1;
  const float* S1 = br ? s1b : s1a;
  __shared__ __align__(16) float encS[4][16 * 40];
  __shared__ __align__(16) float xS[4][16 * 64];
  const int lane = threadIdx.x & 63, wv = threadIdx.x >> 6;
  float* enc = encS[wv];
  float* xL = xS[wv];
  float wreg[36];
#pragma unroll
  for (int c = 0; c < 36; ++c) wreg[c] = W[lane * 36 + c];
  float sreg[64];
#pragma unroll
  for (int c = 0; c < 64; ++c) sreg[c] = S1[lane * 64 + c];
  const float ym = bnp[DS_Y + br * 64 + lane];
  const float ys = bnp[DS_Y + 128 + br * 64 + lane];
  float zs1 = 0.f, zs2 = 0.f;
  const int wid = blockIdx.x * 4 + wv, nw = gridDim.x * 4;
  GATHER_PROLOGUE
#pragma unroll
    for (int k = 0; k < 16; ++k) {
      float xv = (dot36(enc + k * 40, wreg) - ym) * ys;
      xv = xv > 0.f ? xv : 0.f;
      xL[k * 64 + lane] = xv;
    }
    wavefence();
#pragma unroll
    for (int k = 0; k < 16; ++k) {
      const float acc = dot64(xL + k * 64, sreg);
      zs1 += acc; zs2 += acc * acc;
    }
  GATHER_EPILOGUE
  atomicAdd(&dstat[DS_Z + br * 64 + lane], (double)zs1);
  atomicAdd(&dstat[DS_Z + 128 + br * 64 + lane], (double)zs2);
}

// ---------------- passB: full branch -> g = feat @ mw^T raw; g stats --------
// LDS 35.5KB (xS stride 64, mw in bf16 rows stride 68) + launch_bounds(256,4)
// (VGPR<=128) -> 4 blocks/CU, 16 waves (round-7: VGPR 136 capped at 3 blocks).
__global__ __launch_bounds__(256, 4) void passB_kernel(const float* __restrict__ xyz,
                                                       const float* __restrict__ features,
                                                       const int* __restrict__ idx,
                                                       const float* __restrict__ wl1,
                                                       const float* __restrict__ wl2,
                                                       const float* __restrict__ s1a,
                                                       const float* __restrict__ s1b,
                                                       const float* __restrict__ s2a,
                                                       const float* __restrict__ s2b,
                                                       const float* __restrict__ sba,
                                                       const float* __restrict__ sbb,
                                                       const float* __restrict__ mwa,
                                                       const float* __restrict__ mwb,
                                                       const float* __restrict__ bnp,
                                                       double* __restrict__ dstat,
                                                       float* __restrict__ graw) {
  const int br = blockIdx.y;
  const float* W = br ? wl2 : wl1;
  const float* S1 = br ? s1b : s1a;
  const float* S2 = br ? s2b : s2a;
  const float* SB = br ? sbb : sba;
  const float* MW = br ? mwb : mwa;
  __shared__ __align__(16) __hip_bfloat162 mwl2[64 * 34];  // row stride 34 pairs (68 bf16)
  __shared__ __align__(16) float encS[4][16 * 40];
  __shared__ __align__(16) float xS[4][16 * 64];
  __shared__ __align__(16) float featL[4][64];
  for (int t = threadIdx.x; t < 64 * 32; t += 256) {
    const int r = t >> 5, c2 = t & 31;
    __hip_bfloat162 hv;
    hv.x = __float2bfloat16(MW[r * 64 + c2 * 2]);
    hv.y = __float2bfloat16(MW[r * 64 + c2 * 2 + 1]);
    mwl2[r * 34 + c2] = hv;
  }
  __syncthreads();  // one-time weight staging only
  const int lane = threadIdx.x & 63, wv = threadIdx.x >> 6;
  float* enc = encS[wv];
  float* xL = xS[wv];
  const __hip_bfloat162* mrow = mwl2 + lane * 34;
  float wreg[36];
#pragma unroll
  for (int c = 0; c < 36; ++c) wreg[c] = W[lane * 36 + c];
  float sreg[64];
#pragma unroll
  for (int c = 0; c < 64; ++c) sreg[c] = S1[lane * 64 + c];
  const float ym = bnp[DS_Y + br * 64 + lane];
  const float ys = bnp[DS_Y + 128 + br * 64 + lane];
  const float zm = bnp[DS_Z + br * 64 + lane];
  const float zs = bnp[DS_Z + 128 + br * 64 + lane];
  const float sw2r = S2[lane];
  const float sb2v = SB[0];
  float gs1 = 0.f, gs2 = 0.f;
  const int wid = blockIdx.x * 4 + wv, nw = gridDim.x * 4;
  GATHER_PROLOGUE
#pragma unroll
    for (int k = 0; k < 16; ++k) {
      float xv = (dot36(enc + k * 40, wreg) - ym) * ys;
      xv = xv > 0.f ? xv : 0.f;
      xL[k * 64 + lane] = xv;
    }
    wavefence();
    float pl[16];
#pragma unroll
    for (int k = 0; k < 16; ++k) {
      float h = (dot64(xL + k * 64, sreg) - zm) * zs;
      h = h > 0.f ? h : 0.f;
      pl[k] = h * sw2r;
    }
#pragma unroll
    for (int off = 1; off < 64; off <<= 1) {
#pragma unroll
      for (int k = 0; k < 16; ++k) pl[k] += __shfl_xor(pl[k], off, 64);
    }
    float mx = -FLT_MAX;
#pragma unroll
    for (int k = 0; k < 16; ++k) { pl[k] += sb2v; mx = fmaxf(mx, pl[k]); }
    float se = 0.f;
#pragma unroll
    for (int k = 0; k < 16; ++k) { pl[k] = expf(pl[k] - mx); se += pl[k]; }
    const float inv = 1.f / se;
    float f = 0.f;
#pragma unroll
    for (int k = 0; k < 16; ++k) f += xL[k * 64 + lane] * (pl[k] * inv);
    featL[wv][lane] = f;
    wavefence();
    const float* featW = &featL[wv][0];
    float g0 = 0.f, g1 = 0.f, g2 = 0.f, g3 = 0.f;
#pragma unroll
    for (int c8 = 0; c8 < 8; ++c8) {
      const float4 fa = *(const float4*)(featW + c8 * 8);
      const float4 fb = *(const float4*)(featW + c8 * 8 + 4);
      const float2 m0 = __bfloat1622float2(mrow[c8 * 4 + 0]);
      const float2 m1 = __bfloat1622float2(mrow[c8 * 4 + 1]);
      const float2 m2 = __bfloat1622float2(mrow[c8 * 4 + 2]);
      const float2 m3 = __bfloat1622float2(mrow[c8 * 4 + 3]);
      g0 += fa.x * m0.x; g1 += fa.y * m0.y;
      g2 += fa.z * m1.x; g3 += fa.w * m1.y;
      g0 += fb.x * m2.x; g1 += fb.y * m2.y;
      g2 += fb.z * m3.x; g3 += fb.w * m3.y;
    }
    const float g = (g0 + g1) + (g2 + g3);
    graw[((size_t)br * PTS + p) * 64 + lane] = g;
    gs1 += g; gs2 += g * g;
  GATHER_EPILOGUE
  atomicAdd(&dstat[DS_G + br * 64 + lane], (double)gs1);
  atomicAdd(&dstat[DS_G + 128 + br * 64 + lane], (double)gs2);
}

// ---------------- DRB matmul stage (128x128 per-point matvec + stats) -------
__global__ __launch_bounds__(256) void drb_mm_kernel(const float* __restrict__ in,
                                                     const float* __restrict__ wmat,
                                                     const float* __restrict__ bnp,
                                                     double* __restrict__ dstat,
                                                     float* __restrict__ aggout,
                                                     float* __restrict__ rowout,
                                                     int bpIn, int dsOut, int mode) {
  __shared__ __align__(16) float wlds[128 * 129];
  __shared__ __align__(16) float rowS[4][128];
  for (int t = threadIdx.x; t < 128 * 128; t += 256) wlds[(t >> 7) * 129 + (t & 127)] = wmat[t];
  __syncthreads();  // one-time weight staging only
  const int lane = threadIdx.x & 63, wv = threadIdx.x >> 6;
  const float m0 = bnp[bpIn + lane], s0 = bnp[bpIn + 128 + lane];
  const float m1 = bnp[bpIn + 64 + lane], s1 = bnp[bpIn + 128 + 64 + lane];
  float a1s0 = 0.f, a1s1 = 0.f, a2s0 = 0.f, a2s1 = 0.f;
  const int wid = blockIdx.x * 4 + wv, nw = gridDim.x * 4;
  for (int p = wid; p < PTS; p += nw) {
    float v0, v1;
    if (mode == 0) {  // input = g_raw [2][PTS][64]
      v0 = in[(size_t)p * 64 + lane];
      v1 = in[(size_t)PTS * 64 + (size_t)p * 64 + lane];
    } else {          // input = h1 raw [PTS][128]
      v0 = in[(size_t)p * 128 + lane];
      v1 = in[(size_t)p * 128 + 64 + lane];
    }
    v0 = (v0 - m0) * s0; v0 = v0 > 0.f ? v0 : 0.f;
    v1 = (v1 - m1) * s1; v1 = v1 > 0.f ? v1 : 0.f;
    rowS[wv][lane] = v0;
    rowS[wv][64 + lane] = v1;
    if (aggout) {
      aggout[(size_t)p * 128 + lane] = v0;
      aggout[(size_t)p * 128 + 64 + lane] = v1;
    }
    wavefence();
#pragma unroll
    for (int h = 0; h < 2; ++h) {
      const int o = h * 64 + lane;
      float b0 = 0.f, b1 = 0.f, b2 = 0.f, b3 = 0.f;
#pragma unroll
      for (int c4 = 0; c4 < 32; ++c4) {
        const float4 rv = *(const float4*)(&rowS[wv][c4 * 4]);
        b0 += rv.x * wlds[o * 129 + c4 * 4 + 0];
        b1 += rv.y * wlds[o * 129 + c4 * 4 + 1];
        b2 += rv.z * wlds[o * 129 + c4 * 4 + 2];
        b3 += rv.w * wlds[o * 129 + c4 * 4 + 3];
      }
      const float acc = (b0 + b1) + (b2 + b3);
      rowout[(size_t)p * 128 + o] = acc;
      if (h == 0) { a1s0 += acc; a2s0 += acc * acc; }
      else        { a1s1 += acc; a2s1 += acc * acc; }
    }
    wavefence();
  }
  atomicAdd(&dstat[dsOut + lane], (double)a1s0);
  atomicAdd(&dstat[dsOut + 64 + lane], (double)a1s1);
  atomicAdd(&dstat[dsOut + 128 + lane], (double)a2s0);
  atomicAdd(&dstat[dsOut + 128 + 64 + lane], (double)a2s1);
}

// ---------------- final: out = relu(bn(h2) + agg) ---------------------------
__global__ __launch_bounds__(256) void final_kernel(const float* __restrict__ h2,
                                                    const float* __restrict__ agg,
                                                    const float* __restrict__ bnp,
                                                    float* __restrict__ out) {
  const size_t e = (size_t)blockIdx.x * 256 + threadIdx.x;
  const int ch = (int)(e & 127);
  const float m = bnp[DS_H2 + ch], s = bnp[DS_H2 + 128 + ch];
  float v = (h2[e] - m) * s + agg[e];
  out[e] = v > 0.f ? v : 0.f;
}

extern "C" void kernel_launch(void* const* d_in, const int* in_sizes, int n_in,
                              void* d_out, int out_size, void* d_ws, size_t ws_size,
                              hipStream_t stream) {
  (void)in_sizes; (void)n_in; (void)out_size; (void)ws_size;
  const float* xyz      = (const float*)d_in[0];
  const float* features = (const float*)d_in[1];
  const float* w_lse1   = (const float*)d_in[2];
  const float* w_lse2   = (const float*)d_in[3];
  const float* ap1_sw1  = (const float*)d_in[4];
  const float* ap1_sw2  = (const float*)d_in[5];
  const float* ap1_sb2  = (const float*)d_in[6];
  const float* ap1_mw   = (const float*)d_in[7];
  const float* ap2_sw1  = (const float*)d_in[8];
  const float* ap2_sw2  = (const float*)d_in[9];
  const float* ap2_sb2  = (const float*)d_in[10];
  const float* ap2_mw   = (const float*)d_in[11];
  const float* drb_w1   = (const float*)d_in[12];
  const float* drb_w2   = (const float*)d_in[13];

  char* ws = (char*)d_ws;
  float*  knn_d = (float*)(ws + OFF_A);
  int*    knn_j = (int*)(ws + OFF_B);
  int*    idx   = (int*)(ws + OFF_IDX);
  double* dstat = (double*)(ws + OFF_DST);
  float*  mstat = (float*)(ws + OFF_MST);
  float*  bnp   = (float*)(ws + OFF_BNP);
  float*  graw  = (float*)(ws + OFF_A);   // reuse after knn done
  float*  agg   = (float*)(ws + OFF_B);   // reuse after knn done
  float*  h1    = (float*)(ws + OFF_H1);
  float*  h2    = (float*)(ws + OFF_H2);
  float*  out   = (float*)d_out;

  // zero dstat (1280 doubles) + mstat (36*37 floats, contiguous after)
  (void)hipMemsetAsync(dstat, 0, 1280 * sizeof(double) + 36 * 37 * sizeof(float), stream);

  knn_chunk_kernel<<<dim3(Nq / 256, CH, Bq), 256, 0, stream>>>(xyz, knn_d, knn_j);
  knn_merge_kernel<<<dim3(PTS / 256), 256, 0, stream>>>(knn_d, knn_j, idx);

  encM_kernel<<<dim3(1280), 256, 0, stream>>>(xyz, features, idx, mstat);
  y_finalize_kernel<<<1, 128, 0, stream>>>(mstat, w_lse1, w_lse2, bnp);

  passA_kernel<<<dim3(768, 2), 256, 0, stream>>>(xyz, features, idx, w_lse1, w_lse2,
                                                 ap1_sw1, ap2_sw1, bnp, dstat);
  bn_finalize_kernel<<<1, 128, 0, stream>>>(dstat, bnp, DS_Z, 1.0 / ROWS);

  passB_kernel<<<dim3(512, 2), 256, 0, stream>>>(xyz, features, idx, w_lse1, w_lse2,
                                                 ap1_sw1, ap2_sw1, ap1_sw2, ap2_sw2,
                                                 ap1_sb2, ap2_sb2, ap1_mw, ap2_mw,
                                                 bnp, dstat, graw);
  bn_finalize_kernel<<<1, 128, 0, stream>>>(dstat, bnp, DS_G, 1.0 / PTS);

  drb_mm_kernel<<<dim3(512), 256, 0, stream>>>(graw, drb_w1, bnp, dstat, agg, h1,
                                               DS_G, DS_H1, 0);
  bn_finalize_kernel<<<1, 128, 0, stream>>>(dstat, bnp, DS_H1, 1.0 / PTS);

  drb_mm_kernel<<<dim3(512), 256, 0, stream>>>(h1, drb_w2, bnp, dstat, nullptr, h2,
                                               DS_H1, DS_H2, 1);
  bn_finalize_kernel<<<1, 128, 0, stream>>>(dstat, bnp, DS_H2, 1.0 / PTS);

  final_kernel<<<dim3(PTS * 128 / 256), 256, 0, stream>>>(h2, agg, bnp, out);
}

// Round 9
// 1902.402 us; speedup vs baseline: 1.4264x; 1.0864x over previous
//
#include <hip/hip_runtime.h>
#include <hip/hip_bf16.h>
#include <hip/hip_fp16.h>
#include <float.h>
#include <math.h>

#define DEVFN __device__ __forceinline__

// Compiler-only fence: wave64 executes DS ops in order; stops reordering.
DEVFN void wavefence() { __builtin_amdgcn_wave_barrier(); }

namespace {
constexpr int Bq = 4, Nq = 8192, Cq = 32, Kq = 16;
constexpr int PTS = Bq * Nq;          // 32768 points
constexpr int CH = 8;                  // knn candidate chunks
constexpr int CAND = Nq / CH;          // 1024 candidates per chunk
constexpr double ROWS = 524288.0;      // PTS * Kq

// dstat/bnp region bases (each region: [sum|mean x128][sumsq|scale x128])
constexpr int DS_Y = 0, DS_Z = 256, DS_G = 512, DS_H1 = 768, DS_H2 = 1024;

// workspace byte offsets
constexpr size_t OFF_A    = 0;                         // knn_d (16MB) -> reused as g_raw
constexpr size_t OFF_B    = (size_t)16 << 20;          // knn_j (16MB) -> reused as agg
constexpr size_t OFF_IDX  = (size_t)32 << 20;          // idx (2MB)
constexpr size_t OFF_DST  = (size_t)34 << 20;          // dstat (1280 doubles)
constexpr size_t OFF_MST  = ((size_t)34 << 20) + 10240; // mstat (36*37 floats)
constexpr size_t OFF_BNP  = ((size_t)34 << 20) + 16384; // bnp (1280 floats)
constexpr size_t OFF_H1   = ((size_t)34 << 20) + 32768; // h1 raw (16MB)
constexpr size_t OFF_H2   = ((size_t)50 << 20) + 32768; // h2 raw (16MB)
}

// ---------------- KNN: two-phase select-then-collect ------------------------
#define TOP16_DECL                                                           \
  float e0=FLT_MAX,e1=FLT_MAX,e2=FLT_MAX,e3=FLT_MAX,e4=FLT_MAX,e5=FLT_MAX,  \
        e6=FLT_MAX,e7=FLT_MAX,e8=FLT_MAX,e9=FLT_MAX,e10=FLT_MAX,            \
        e11=FLT_MAX,e12=FLT_MAX,e13=FLT_MAX,e14=FLT_MAX,e15=FLT_MAX;

#define TINS(i) { const float lo = fminf(e##i, u); u = fmaxf(e##i, u); e##i = lo; }
#define TINS_ALL  TINS(0) TINS(1) TINS(2) TINS(3) TINS(4) TINS(5) TINS(6)    \
                  TINS(7) TINS(8) TINS(9) TINS(10) TINS(11) TINS(12)         \
                  TINS(13) TINS(14) TINS(15)

DEVFN float distf(const float4 c, const float qx, const float qy, const float qz) {
  const float dx = qx - c.x, dy = qy - c.y, dz = qz - c.z;
  return __fadd_rn(__fadd_rn(__fmul_rn(dx, dx), __fmul_rn(dy, dy)), __fmul_rn(dz, dz));
}

__global__ __launch_bounds__(256, 4) void knn_chunk_kernel(const float* __restrict__ xyz,
                                                           float* __restrict__ pd,
                                                           int* __restrict__ pj) {
  const int b = blockIdx.z;
  const int ch = blockIdx.y;
  const int n = blockIdx.x * 256 + threadIdx.x;
  __shared__ __align__(16) float4 tile[CAND];
  const float* xb = xyz + (size_t)b * Nq * 3;
  for (int t = threadIdx.x; t < CAND; t += 256) {
    const int j = ch * CAND + t;
    tile[t] = make_float4(xb[j * 3], xb[j * 3 + 1], xb[j * 3 + 2], 0.f);
  }
  __syncthreads();
  const float qx = xb[n * 3], qy = xb[n * 3 + 1], qz = xb[n * 3 + 2];
  TOP16_DECL;
  for (int t = 0; t < CAND; ++t) {
    float u = distf(tile[t], qx, qy, qz);
    TINS_ALL
  }
  const float kth = e15;
  const size_t base = (((size_t)b * Nq + n) * CH + ch) * Kq;
  int cnt = 0;
  for (int t = 0; t < CAND; ++t) {
    const float d = distf(tile[t], qx, qy, qz);
    if (d < kth) { pd[base + cnt] = d; pj[base + cnt] = ch * CAND + t; ++cnt; }
  }
  // tie scan with wave-uniform early exit (tie position ~uniform -> skip ~half)
  for (int t0 = 0; t0 < CAND; t0 += 128) {
    if (!__any(cnt < 16)) break;
    const int tend = t0 + 128;
    for (int t = t0; t < tend; ++t) {
      const float d = distf(tile[t], qx, qy, qz);
      if (d == kth && cnt < 16) { pd[base + cnt] = d; pj[base + cnt] = ch * CAND + t; ++cnt; }
    }
  }
}

__global__ __launch_bounds__(256, 4) void knn_merge_kernel(const float* __restrict__ pd,
                                                           const int* __restrict__ pj,
                                                           int* __restrict__ idxo) {
  const int q = blockIdx.x * 256 + threadIdx.x;
  const float* dp = pd + (size_t)q * CH * Kq;
  const int* jp = pj + (size_t)q * CH * Kq;
  TOP16_DECL;
  for (int t = 0; t < CH * Kq; t += 4) {
    const float4 v = *(const float4*)(dp + t);
    { float u = v.x; TINS_ALL }
    { float u = v.y; TINS_ALL }
    { float u = v.z; TINS_ALL }
    { float u = v.w; TINS_ALL }
  }
  const float kth = e15;
  int* op = idxo + (size_t)q * Kq;
  int cnt = 0;
  for (int t = 0; t < CH * Kq; ++t) {
    const float d = dp[t];
    if (d < kth) { op[cnt] = jp[t]; ++cnt; }
  }
  for (int t = 0; t < CH * Kq; ++t) {
    const float d = dp[t];
    if (d == kth && cnt < 16) { op[cnt] = jp[t]; ++cnt; }
  }
}

// ---------------- gather pipeline pieces ------------------------------------
struct PF { float4 f0, f1; float nx, ny, nz; };

DEVFN PF issue_feat(const float* __restrict__ features, const float* __restrict__ xyz,
                    int p, int j, int sub) {
  const int b = p >> 13;
  const float* fr = features + ((size_t)b * Nq + j) * Cq;
  const float* xb = xyz + ((size_t)b * Nq + j) * 3;
  PF r;
  r.f0 = *(const float4*)(fr + sub * 8);
  r.f1 = *(const float4*)(fr + sub * 8 + 4);
  r.nx = xb[0]; r.ny = xb[1]; r.nz = xb[2];
  return r;
}

DEVFN int issue_idx(const int* __restrict__ idx, int p, int lane) {
  return idx[(size_t)p * Kq + (lane >> 2)];
}

DEVFN float3 issue_query(const float* __restrict__ xyz, int p) {
  const float* q = xyz + (size_t)p * 3;  // [B,N,3] flat: p = b*Nq+n
  return make_float3(q[0], q[1], q[2]);
}

// enc row layout: [rel.x rel.y rel.z dist f0..f31] padded to 40 floats.
DEVFN void commit_enc(float* __restrict__ enc, int lane, const PF& pf,
                      float qx, float qy, float qz) {
  const int k = lane >> 2, sub = lane & 3;
  float* er = enc + k * 40;
  *(float4*)(er + 4 + sub * 8) = pf.f0;
  *(float4*)(er + 4 + sub * 8 + 4) = pf.f1;
  if (sub == 0) {
    const float rx = pf.nx - qx, ry = pf.ny - qy, rz = pf.nz - qz;
    const float ss = rx * rx + ry * ry + rz * rz;
    *(float4*)er = make_float4(rx, ry, rz, sqrtf(fmaxf(ss, 1e-12f)));
  }
}

// dot(enc_row[0..35], f16-packed weights) -- 4 accumulators; float(half)*float
// pattern fuses to v_fma_mix (no spill: 18 VGPRs vs 36 for fp32 weights).
DEVFN float dot36h(const float* __restrict__ er, const __half2* __restrict__ wh) {
  float a0 = 0.f, a1 = 0.f, a2 = 0.f, a3 = 0.f;
#pragma unroll
  for (int c4 = 0; c4 < 9; ++c4) {
    const float4 ev = *(const float4*)(er + c4 * 4);
    const __half2 w0 = wh[c4 * 2], w1 = wh[c4 * 2 + 1];
    a0 += ev.x * __low2float(w0);
    a1 += ev.y * __high2float(w0);
    a2 += ev.z * __low2float(w1);
    a3 += ev.w * __high2float(w1);
  }
  return (a0 + a1) + (a2 + a3);
}

// dot(x_row[0..63], f16-packed weights) -- 32 VGPRs vs 64 for fp32.
DEVFN float dot64h(const float* __restrict__ xr, const __half2* __restrict__ sh) {
  float a0 = 0.f, a1 = 0.f, a2 = 0.f, a3 = 0.f;
#pragma unroll
  for (int c4 = 0; c4 < 16; ++c4) {
    const float4 xv = *(const float4*)(xr + c4 * 4);
    const __half2 s0 = sh[c4 * 2], s1 = sh[c4 * 2 + 1];
    a0 += xv.x * __low2float(s0);
    a1 += xv.y * __high2float(s0);
    a2 += xv.z * __low2float(s1);
    a3 += xv.w * __high2float(s1);
  }
  return (a0 + a1) + (a2 + a3);
}

// pipeline open/close macros (body sits between them as ordinary code).
#define GATHER_PROLOGUE                                                      \
  int p = wid;                                                               \
  int jc = issue_idx(idx, p, lane);                                          \
  PF cur = issue_feat(features, xyz, p, jc, lane & 3);                       \
  float3 qc = issue_query(xyz, p);                                           \
  int pn0 = p + nw; if (pn0 >= PTS) pn0 = p;                                 \
  int jn = issue_idx(idx, pn0, lane);                                        \
  float3 qn = issue_query(xyz, pn0);                                         \
  for (; p < PTS; p += nw) {                                                 \
    int pn = p + nw; if (pn >= PTS) pn = p;                                  \
    int pn2 = pn + nw; if (pn2 >= PTS) pn2 = pn;                             \
    PF nxt = issue_feat(features, xyz, pn, jn, lane & 3);                    \
    const int jn2 = issue_idx(idx, pn2, lane);                               \
    const float3 q2 = issue_query(xyz, pn2);                                 \
    commit_enc(enc, lane, cur, qc.x, qc.y, qc.z);                            \
    wavefence();

#define GATHER_EPILOGUE                                                      \
    wavefence();                                                             \
    cur = nxt; qc = qn; qn = q2; jn = jn2;                                   \
  }

// ---------------- encM: M = sum enc^T enc (36x36), v = sum enc --------------
__global__ __launch_bounds__(256) void encM_kernel(const float* __restrict__ xyz,
                                                   const float* __restrict__ features,
                                                   const int* __restrict__ idx,
                                                   float* __restrict__ mstat) {
  __shared__ __align__(16) float encS[4][16 * 40];
  __shared__ float mred[4][36 * 37];
  const int lane = threadIdx.x & 63, wv = threadIdx.x >> 6;
  float* enc = encS[wv];
  const int li = (lane < 36) ? lane : 0;  // clamp: lanes>=36 compute junk, never stored
  float macc[36];
#pragma unroll
  for (int i = 0; i < 36; ++i) macc[i] = 0.f;
  float vacc = 0.f;
  const int wid = blockIdx.x * 4 + wv, nw = gridDim.x * 4;
  GATHER_PROLOGUE
#pragma unroll
    for (int k = 0; k < 16; ++k) {
      const float* er = enc + k * 40;
      const float ei = er[li];
      vacc += ei;
#pragma unroll
      for (int c4 = 0; c4 < 9; ++c4) {
        const float4 ev = *(const float4*)(er + c4 * 4);
        macc[c4 * 4 + 0] += ei * ev.x;
        macc[c4 * 4 + 1] += ei * ev.y;
        macc[c4 * 4 + 2] += ei * ev.z;
        macc[c4 * 4 + 3] += ei * ev.w;
      }
    }
  GATHER_EPILOGUE
  if (lane < 36) {
#pragma unroll
    for (int j = 0; j < 36; ++j) mred[wv][lane * 37 + j] = macc[j];
    mred[wv][lane * 37 + 36] = vacc;
  }
  __syncthreads();
  for (int t = threadIdx.x; t < 36 * 37; t += 256) {
    const float s = mred[0][t] + mred[1][t] + mred[2][t] + mred[3][t];
    atomicAdd(&mstat[t], s);
  }
}

// y-stat finalize from moments (double precision). thread t = br*64+o.
__global__ void y_finalize_kernel(const float* __restrict__ mstat,
                                  const float* __restrict__ wl1,
                                  const float* __restrict__ wl2,
                                  float* __restrict__ bnp) {
  const int t = threadIdx.x;  // 128
  const int br = t >> 6, o = t & 63;
  const float* W = br ? wl2 : wl1;
  double wrow[36];
  for (int c = 0; c < 36; ++c) wrow[c] = (double)W[o * 36 + c];
  double mean = 0.0, ey2 = 0.0;
  for (int i = 0; i < 36; ++i) {
    mean += wrow[i] * (double)mstat[i * 37 + 36];
    double rowacc = 0.0;
    for (int j = 0; j < 36; ++j) rowacc += wrow[j] * (double)mstat[i * 37 + j];
    ey2 += wrow[i] * rowacc;
  }
  const double invR = 1.0 / ROWS;
  mean *= invR; ey2 *= invR;
  const double var = ey2 - mean * mean;
  bnp[DS_Y + br * 64 + o] = (float)mean;
  bnp[DS_Y + 128 + br * 64 + o] = (float)(1.0 / sqrt(var + 1e-5));
}

// ---------------- generic BN stat finalize: mean + rsqrt(var+eps) -----------
__global__ void bn_finalize_kernel(const double* __restrict__ dstat, float* __restrict__ bnp,
                                   int base, double invc) {
  const int t = threadIdx.x;  // 128 threads
  const double m = dstat[base + t] * invc;
  const double v = dstat[base + 128 + t] * invc - m * m;
  bnp[base + t] = (float)m;
  bnp[base + 128 + t] = (float)(1.0 / sqrt(v + 1e-5));
}

// ---------------- passA: x = relu(bn(y)); z = x @ sw1^T; z stats ------------
// f16 weight regs (wh 18 + sh 32 VGPRs) -> no spill at (256,4): 16 waves/CU.
__global__ __launch_bounds__(256, 4) void passA_kernel(const float* __restrict__ xyz,
                                                       const float* __restrict__ features,
                                                       const int* __restrict__ idx,
                                                       const float* __restrict__ wl1,
                                                       const float* __restrict__ wl2,
                                                       const float* __restrict__ s1a,
                                                       const float* __restrict__ s1b,
                                                       const float* __restrict__ bnp,
                                                       double* __restrict__ dstat) {
  const int br = blockIdx.y;
  const float* W = br ? wl2 : wl1;
  const float* S1 = br ? s1b : s1a;
  __shared__ __align__(16) float encS[4][16 * 40];
  __shared__ __align__(16) float xS[4][16 * 64];
  const int lane = threadIdx.x & 63, wv = threadIdx.x >> 6;
  float* enc = encS[wv];
  float* xL = xS[wv];
  __half2 wh[18];
#pragma unroll
  for (int c = 0; c < 18; ++c)
    wh[c] = __floats2half2_rn(W[lane * 36 + 2 * c], W[lane * 36 + 2 * c + 1]);
  __half2 sh[32];
#pragma unroll
  for (int c = 0; c < 32; ++c)
    sh[c] = __floats2half2_rn(S1[lane * 64 + 2 * c], S1[lane * 64 + 2 * c + 1]);
  const float ym = bnp[DS_Y + br * 64 + lane];
  const float ys = bnp[DS_Y + 128 + br * 64 + lane];
  float zs1 = 0.f, zs2 = 0.f;
  const int wid = blockIdx.x * 4 + wv, nw = gridDim.x * 4;
  GATHER_PROLOGUE
#pragma unroll
    for (int k = 0; k < 16; ++k) {
      float xv = (dot36h(enc + k * 40, wh) - ym) * ys;
      xv = xv > 0.f ? xv : 0.f;
      xL[k * 64 + lane] = xv;
    }
    wavefence();
#pragma unroll
    for (int k = 0; k < 16; ++k) {
      const float acc = dot64h(xL + k * 64, sh);
      zs1 += acc; zs2 += acc * acc;
    }
  GATHER_EPILOGUE
  atomicAdd(&dstat[DS_Z + br * 64 + lane], (double)zs1);
  atomicAdd(&dstat[DS_Z + 128 + br * 64 + lane], (double)zs2);
}

// ---------------- passB: full branch -> g = feat @ mw^T raw; g stats --------
// Round-8 post-mortem: (256,4) with fp32 weight regs spilled wreg+sreg ->
// 1.85GB scratch HBM traffic (FETCH 963MB), VALUBusy 5.6%. f16-packed weight
// regs fit the 128-VGPR budget -> 16 waves/CU with zero spill.
__global__ __launch_bounds__(256, 4) void passB_kernel(const float* __restrict__ xyz,
                                                       const float* __restrict__ features,
                                                       const int* __restrict__ idx,
                                                       const float* __restrict__ wl1,
                                                       const float* __restrict__ wl2,
                                                       const float* __restrict__ s1a,
                                                       const float* __restrict__ s1b,
                                                       const float* __restrict__ s2a,
                                                       const float* __restrict__ s2b,
                                                       const float* __restrict__ sba,
                                                       const float* __restrict__ sbb,
                                                       const float* __restrict__ mwa,
                                                       const float* __restrict__ mwb,
                                                       const float* __restrict__ bnp,
                                                       double* __restrict__ dstat,
                                                       float* __restrict__ graw) {
  const int br = blockIdx.y;
  const float* W = br ? wl2 : wl1;
  const float* S1 = br ? s1b : s1a;
  const float* S2 = br ? s2b : s2a;
  const float* SB = br ? sbb : sba;
  const float* MW = br ? mwb : mwa;
  __shared__ __align__(16) __half2 mwl2[64 * 34];  // row stride 34 pairs (68 halves)
  __shared__ __align__(16) float encS[4][16 * 40];
  __shared__ __align__(16) float xS[4][16 * 64];
  __shared__ __align__(16) float featL[4][64];
  for (int t = threadIdx.x; t < 64 * 32; t += 256) {
    const int r = t >> 5, c2 = t & 31;
    mwl2[r * 34 + c2] = __floats2half2_rn(MW[r * 64 + c2 * 2], MW[r * 64 + c2 * 2 + 1]);
  }
  __syncthreads();  // one-time weight staging only
  const int lane = threadIdx.x & 63, wv = threadIdx.x >> 6;
  float* enc = encS[wv];
  float* xL = xS[wv];
  const __half2* mrow = mwl2 + lane * 34;
  __half2 wh[18];
#pragma unroll
  for (int c = 0; c < 18; ++c)
    wh[c] = __floats2half2_rn(W[lane * 36 + 2 * c], W[lane * 36 + 2 * c + 1]);
  __half2 sh[32];
#pragma unroll
  for (int c = 0; c < 32; ++c)
    sh[c] = __floats2half2_rn(S1[lane * 64 + 2 * c], S1[lane * 64 + 2 * c + 1]);
  const float ym = bnp[DS_Y + br * 64 + lane];
  const float ys = bnp[DS_Y + 128 + br * 64 + lane];
  const float zm = bnp[DS_Z + br * 64 + lane];
  const float zs = bnp[DS_Z + 128 + br * 64 + lane];
  const float sw2r = S2[lane];
  const float sb2v = SB[0];
  float gs1 = 0.f, gs2 = 0.f;
  const int wid = blockIdx.x * 4 + wv, nw = gridDim.x * 4;
  GATHER_PROLOGUE
#pragma unroll
    for (int k = 0; k < 16; ++k) {
      float xv = (dot36h(enc + k * 40, wh) - ym) * ys;
      xv = xv > 0.f ? xv : 0.f;
      xL[k * 64 + lane] = xv;
    }
    wavefence();
    float pl[16];
#pragma unroll
    for (int k = 0; k < 16; ++k) {
      float h = (dot64h(xL + k * 64, sh) - zm) * zs;
      h = h > 0.f ? h : 0.f;
      pl[k] = h * sw2r;
    }
#pragma unroll
    for (int off = 1; off < 64; off <<= 1) {
#pragma unroll
      for (int k = 0; k < 16; ++k) pl[k] += __shfl_xor(pl[k], off, 64);
    }
    float mx = -FLT_MAX;
#pragma unroll
    for (int k = 0; k < 16; ++k) { pl[k] += sb2v; mx = fmaxf(mx, pl[k]); }
    float se = 0.f;
#pragma unroll
    for (int k = 0; k < 16; ++k) { pl[k] = expf(pl[k] - mx); se += pl[k]; }
    const float inv = 1.f / se;
    float f = 0.f;
#pragma unroll
    for (int k = 0; k < 16; ++k) f += xL[k * 64 + lane] * (pl[k] * inv);
    featL[wv][lane] = f;
    wavefence();
    const float* featW = &featL[wv][0];
    float g0 = 0.f, g1 = 0.f, g2 = 0.f, g3 = 0.f;
#pragma unroll
    for (int c8 = 0; c8 < 8; ++c8) {
      const float4 fa = *(const float4*)(featW + c8 * 8);
      const float4 fb = *(const float4*)(featW + c8 * 8 + 4);
      const __half2 m0 = mrow[c8 * 4 + 0];
      const __half2 m1 = mrow[c8 * 4 + 1];
      const __half2 m2 = mrow[c8 * 4 + 2];
      const __half2 m3 = mrow[c8 * 4 + 3];
      g0 += fa.x * __low2float(m0); g1 += fa.y * __high2float(m0);
      g2 += fa.z * __low2float(m1); g3 += fa.w * __high2float(m1);
      g0 += fb.x * __low2float(m2); g1 += fb.y * __high2float(m2);
      g2 += fb.z * __low2float(m3); g3 += fb.w * __high2float(m3);
    }
    const float g = (g0 + g1) + (g2 + g3);
    graw[((size_t)br * PTS + p) * 64 + lane] = g;
    gs1 += g; gs2 += g * g;
  GATHER_EPILOGUE
  atomicAdd(&dstat[DS_G + br * 64 + lane], (double)gs1);
  atomicAdd(&dstat[DS_G + 128 + br * 64 + lane], (double)gs2);
}

// ---------------- DRB matmul stage (128x128 per-point matvec + stats) -------
__global__ __launch_bounds__(256) void drb_mm_kernel(const float* __restrict__ in,
                                                     const float* __restrict__ wmat,
                                                     const float* __restrict__ bnp,
                                                     double* __restrict__ dstat,
                                                     float* __restrict__ aggout,
                                                     float* __restrict__ rowout,
                                                     int bpIn, int dsOut, int mode) {
  __shared__ __align__(16) float wlds[128 * 129];
  __shared__ __align__(16) float rowS[4][128];
  for (int t = threadIdx.x; t < 128 * 128; t += 256) wlds[(t >> 7) * 129 + (t & 127)] = wmat[t];
  __syncthreads();  // one-time weight staging only
  const int lane = threadIdx.x & 63, wv = threadIdx.x >> 6;
  const float m0 = bnp[bpIn + lane], s0 = bnp[bpIn + 128 + lane];
  const float m1 = bnp[bpIn + 64 + lane], s1 = bnp[bpIn + 128 + 64 + lane];
  float a1s0 = 0.f, a1s1 = 0.f, a2s0 = 0.f, a2s1 = 0.f;
  const int wid = blockIdx.x * 4 + wv, nw = gridDim.x * 4;
  for (int p = wid; p < PTS; p += nw) {
    float v0, v1;
    if (mode == 0) {  // input = g_raw [2][PTS][64]
      v0 = in[(size_t)p * 64 + lane];
      v1 = in[(size_t)PTS * 64 + (size_t)p * 64 + lane];
    } else {          // input = h1 raw [PTS][128]
      v0 = in[(size_t)p * 128 + lane];
      v1 = in[(size_t)p * 128 + 64 + lane];
    }
    v0 = (v0 - m0) * s0; v0 = v0 > 0.f ? v0 : 0.f;
    v1 = (v1 - m1) * s1; v1 = v1 > 0.f ? v1 : 0.f;
    rowS[wv][lane] = v0;
    rowS[wv][64 + lane] = v1;
    if (aggout) {
      aggout[(size_t)p * 128 + lane] = v0;
      aggout[(size_t)p * 128 + 64 + lane] = v1;
    }
    wavefence();
#pragma unroll
    for (int h = 0; h < 2; ++h) {
      const int o = h * 64 + lane;
      float b0 = 0.f, b1 = 0.f, b2 = 0.f, b3 = 0.f;
#pragma unroll
      for (int c4 = 0; c4 < 32; ++c4) {
        const float4 rv = *(const float4*)(&rowS[wv][c4 * 4]);
        b0 += rv.x * wlds[o * 129 + c4 * 4 + 0];
        b1 += rv.y * wlds[o * 129 + c4 * 4 + 1];
        b2 += rv.z * wlds[o * 129 + c4 * 4 + 2];
        b3 += rv.w * wlds[o * 129 + c4 * 4 + 3];
      }
      const float acc = (b0 + b1) + (b2 + b3);
      rowout[(size_t)p * 128 + o] = acc;
      if (h == 0) { a1s0 += acc; a2s0 += acc * acc; }
      else        { a1s1 += acc; a2s1 += acc * acc; }
    }
    wavefence();
  }
  atomicAdd(&dstat[dsOut + lane], (double)a1s0);
  atomicAdd(&dstat[dsOut + 64 + lane], (double)a1s1);
  atomicAdd(&dstat[dsOut + 128 + lane], (double)a2s0);
  atomicAdd(&dstat[dsOut + 128 + 64 + lane], (double)a2s1);
}

// ---------------- final: out = relu(bn(h2) + agg) ---------------------------
__global__ __launch_bounds__(256) void final_kernel(const float* __restrict__ h2,
                                                    const float* __restrict__ agg,
                                                    const float* __restrict__ bnp,
                                                    float* __restrict__ out) {
  const size_t e = (size_t)blockIdx.x * 256 + threadIdx.x;
  const int ch = (int)(e & 127);
  const float m = bnp[DS_H2 + ch], s = bnp[DS_H2 + 128 + ch];
  float v = (h2[e] - m) * s + agg[e];
  out[e] = v > 0.f ? v : 0.f;
}

extern "C" void kernel_launch(void* const* d_in, const int* in_sizes, int n_in,
                              void* d_out, int out_size, void* d_ws, size_t ws_size,
                              hipStream_t stream) {
  (void)in_sizes; (void)n_in; (void)out_size; (void)ws_size;
  const float* xyz      = (const float*)d_in[0];
  const float* features = (const float*)d_in[1];
  const float* w_lse1   = (const float*)d_in[2];
  const float* w_lse2   = (const float*)d_in[3];
  const float* ap1_sw1  = (const float*)d_in[4];
  const float* ap1_sw2  = (const float*)d_in[5];
  const float* ap1_sb2  = (const float*)d_in[6];
  const float* ap1_mw   = (const float*)d_in[7];
  const float* ap2_sw1  = (const float*)d_in[8];
  const float* ap2_sw2  = (const float*)d_in[9];
  const float* ap2_sb2  = (const float*)d_in[10];
  const float* ap2_mw   = (const float*)d_in[11];
  const float* drb_w1   = (const float*)d_in[12];
  const float* drb_w2   = (const float*)d_in[13];

  char* ws = (char*)d_ws;
  float*  knn_d = (float*)(ws + OFF_A);
  int*    knn_j = (int*)(ws + OFF_B);
  int*    idx   = (int*)(ws + OFF_IDX);
  double* dstat = (double*)(ws + OFF_DST);
  float*  mstat = (float*)(ws + OFF_MST);
  float*  bnp   = (float*)(ws + OFF_BNP);
  float*  graw  = (float*)(ws + OFF_A);   // reuse after knn done
  float*  agg   = (float*)(ws + OFF_B);   // reuse after knn done
  float*  h1    = (float*)(ws + OFF_H1);
  float*  h2    = (float*)(ws + OFF_H2);
  float*  out   = (float*)d_out;

  // zero dstat (1280 doubles) + mstat (36*37 floats, contiguous after)
  (void)hipMemsetAsync(dstat, 0, 1280 * sizeof(double) + 36 * 37 * sizeof(float), stream);

  knn_chunk_kernel<<<dim3(Nq / 256, CH, Bq), 256, 0, stream>>>(xyz, knn_d, knn_j);
  knn_merge_kernel<<<dim3(PTS / 256), 256, 0, stream>>>(knn_d, knn_j, idx);

  encM_kernel<<<dim3(1280), 256, 0, stream>>>(xyz, features, idx, mstat);
  y_finalize_kernel<<<1, 128, 0, stream>>>(mstat, w_lse1, w_lse2, bnp);

  passA_kernel<<<dim3(512, 2), 256, 0, stream>>>(xyz, features, idx, w_lse1, w_lse2,
                                                 ap1_sw1, ap2_sw1, bnp, dstat);
  bn_finalize_kernel<<<1, 128, 0, stream>>>(dstat, bnp, DS_Z, 1.0 / ROWS);

  passB_kernel<<<dim3(512, 2), 256, 0, stream>>>(xyz, features, idx, w_lse1, w_lse2,
                                                 ap1_sw1, ap2_sw1, ap1_sw2, ap2_sw2,
                                                 ap1_sb2, ap2_sb2, ap1_mw, ap2_mw,
                                                 bnp, dstat, graw);
  bn_finalize_kernel<<<1, 128, 0, stream>>>(dstat, bnp, DS_G, 1.0 / PTS);

  drb_mm_kernel<<<dim3(512), 256, 0, stream>>>(graw, drb_w1, bnp, dstat, agg, h1,
                                               DS_G, DS_H1, 0);
  bn_finalize_kernel<<<1, 128, 0, stream>>>(dstat, bnp, DS_H1, 1.0 / PTS);

  drb_mm_kernel<<<dim3(512), 256, 0, stream>>>(h1, drb_w2, bnp, dstat, nullptr, h2,
                                               DS_H1, DS_H2, 1);
  bn_finalize_kernel<<<1, 128, 0, stream>>>(dstat, bnp, DS_H2, 1.0 / PTS);

  final_kernel<<<dim3(PTS * 128 / 256), 256, 0, stream>>>(h2, agg, bnp, out);
}

// Round 10
// 1719.318 us; speedup vs baseline: 1.5783x; 1.1065x over previous
//
#include <hip/hip_runtime.h>
#include <hip/hip_bf16.h>
#include <hip/hip_fp16.h>
#include <float.h>
#include <math.h>

#define DEVFN __device__ __forceinline__

// Compiler-only fence: wave64 executes DS ops in order; stops reordering.
DEVFN void wavefence() { __builtin_amdgcn_wave_barrier(); }

namespace {
constexpr int Bq = 4, Nq = 8192, Cq = 32, Kq = 16;
constexpr int PTS = Bq * Nq;          // 32768 points
constexpr int CH = 8;                  // knn candidate chunks
constexpr int CAND = Nq / CH;          // 1024 candidates per chunk
constexpr double ROWS = 524288.0;      // PTS * Kq

// dstat/bnp region bases (each region: [sum|mean x128][sumsq|scale x128])
constexpr int DS_Y = 0, DS_Z = 256, DS_G = 512, DS_H1 = 768, DS_H2 = 1024;

// workspace byte offsets
constexpr size_t OFF_A    = 0;                         // knn_d (16MB) -> reused as g_raw
constexpr size_t OFF_B    = (size_t)16 << 20;          // knn_j (16MB) -> reused as agg
constexpr size_t OFF_IDX  = (size_t)32 << 20;          // idx (2MB)
constexpr size_t OFF_DST  = (size_t)34 << 20;          // dstat (1280 doubles)
constexpr size_t OFF_MST  = ((size_t)34 << 20) + 10240; // mstat (36*37 floats)
constexpr size_t OFF_BNP  = ((size_t)34 << 20) + 16384; // bnp (1280 floats)
constexpr size_t OFF_H1   = ((size_t)34 << 20) + 32768; // h1 raw (16MB)
constexpr size_t OFF_H2   = ((size_t)50 << 20) + 32768; // h2 raw (16MB)
}

// ---------------- KNN: two-phase select-then-collect ------------------------
#define TOP16_DECL                                                           \
  float e0=FLT_MAX,e1=FLT_MAX,e2=FLT_MAX,e3=FLT_MAX,e4=FLT_MAX,e5=FLT_MAX,  \
        e6=FLT_MAX,e7=FLT_MAX,e8=FLT_MAX,e9=FLT_MAX,e10=FLT_MAX,            \
        e11=FLT_MAX,e12=FLT_MAX,e13=FLT_MAX,e14=FLT_MAX,e15=FLT_MAX;

#define TINS(i) { const float lo = fminf(e##i, u); u = fmaxf(e##i, u); e##i = lo; }
#define TINS_ALL  TINS(0) TINS(1) TINS(2) TINS(3) TINS(4) TINS(5) TINS(6)    \
                  TINS(7) TINS(8) TINS(9) TINS(10) TINS(11) TINS(12)         \
                  TINS(13) TINS(14) TINS(15)

// Pair-merge: merge sorted e0..e15 with sorted pair (b0<=b1), keep 16 smallest.
// R[i] = min3(e_i, max(e_{i-1},b0), max(e_{i-2},b1)); evaluate top-down so each
// line reads only old (lower-index) values. min3/max fuse to v_min3/v_max.
#define PMERGE(i, im1, im2)                                                  \
  e##i = fminf(fminf(e##i, fmaxf(e##im1, b0)), fmaxf(e##im2, b1));
#define PMERGE_ALL                                                           \
  PMERGE(15,14,13) PMERGE(14,13,12) PMERGE(13,12,11) PMERGE(12,11,10)        \
  PMERGE(11,10,9) PMERGE(10,9,8) PMERGE(9,8,7) PMERGE(8,7,6) PMERGE(7,6,5)   \
  PMERGE(6,5,4) PMERGE(5,4,3) PMERGE(4,3,2) PMERGE(3,2,1) PMERGE(2,1,0)      \
  e1 = fminf(fminf(e1, fmaxf(e0, b0)), b1);                                  \
  e0 = fminf(e0, b0);

DEVFN float distf(const float4 c, const float qx, const float qy, const float qz) {
  const float dx = qx - c.x, dy = qy - c.y, dz = qz - c.z;
  return __fadd_rn(__fadd_rn(__fmul_rn(dx, dx), __fmul_rn(dy, dy)), __fmul_rn(dz, dz));
}

__global__ __launch_bounds__(256, 4) void knn_chunk_kernel(const float* __restrict__ xyz,
                                                           float* __restrict__ pd,
                                                           int* __restrict__ pj) {
  const int b = blockIdx.z;
  const int ch = blockIdx.y;
  const int n = blockIdx.x * 256 + threadIdx.x;
  __shared__ __align__(16) float4 tile[CAND];
  const float* xb = xyz + (size_t)b * Nq * 3;
  for (int t = threadIdx.x; t < CAND; t += 256) {
    const int j = ch * CAND + t;
    tile[t] = make_float4(xb[j * 3], xb[j * 3 + 1], xb[j * 3 + 2], 0.f);
  }
  __syncthreads();
  const float qx = xb[n * 3], qy = xb[n * 3 + 1], qz = xb[n * 3 + 2];
  // scan 1: 16 smallest distance VALUES via pair-merge network (values only ->
  // ~20 VGPR state, no scratch; round-9 profile: VALU-issue bound at 81%).
  TOP16_DECL;
  for (int t = 0; t < CAND; t += 2) {
    const float u0 = distf(tile[t], qx, qy, qz);
    const float u1 = distf(tile[t + 1], qx, qy, qz);
    const float b0 = fminf(u0, u1), b1 = fmaxf(u0, u1);
    PMERGE_ALL
  }
  const float kth = e15;
  // scan 2: collect indices d < kth (ascending order == stable top_k) and
  // fold the tie search in: record first index with d == kth branch-free.
  const size_t base = (((size_t)b * Nq + n) * CH + ch) * Kq;
  int cnt = 0, tfirst = -1;
  for (int t = 0; t < CAND; ++t) {
    const float d = distf(tile[t], qx, qy, qz);
    if (d < kth) { pd[base + cnt] = d; pj[base + cnt] = ch * CAND + t; ++cnt; }
    tfirst = (d == kth && tfirst < 0) ? t : tfirst;
  }
  if (cnt == 15) {  // typical (all-distinct): exactly one kth tie -> done
    pd[base + 15] = kth; pj[base + 15] = ch * CAND + tfirst; cnt = 16;
  }
  if (__any(cnt < 16)) {  // rare multi-tie fallback (exactness)
    for (int t = 0; t < CAND; ++t) {
      const float d = distf(tile[t], qx, qy, qz);
      if (d == kth && cnt < 16) { pd[base + cnt] = d; pj[base + cnt] = ch * CAND + t; ++cnt; }
    }
  }
}

__global__ __launch_bounds__(256, 4) void knn_merge_kernel(const float* __restrict__ pd,
                                                           const int* __restrict__ pj,
                                                           int* __restrict__ idxo) {
  const int q = blockIdx.x * 256 + threadIdx.x;
  const float* dp = pd + (size_t)q * CH * Kq;
  const int* jp = pj + (size_t)q * CH * Kq;
  TOP16_DECL;
  for (int t = 0; t < CH * Kq; t += 4) {
    const float4 v = *(const float4*)(dp + t);
    { const float b0 = fminf(v.x, v.y), b1 = fmaxf(v.x, v.y); PMERGE_ALL }
    { const float b0 = fminf(v.z, v.w), b1 = fmaxf(v.z, v.w); PMERGE_ALL }
  }
  const float kth = e15;
  int* op = idxo + (size_t)q * Kq;
  int cnt = 0;
  for (int t = 0; t < CH * Kq; ++t) {
    const float d = dp[t];
    if (d < kth) { op[cnt] = jp[t]; ++cnt; }
  }
  for (int t = 0; t < CH * Kq; ++t) {
    const float d = dp[t];
    if (d == kth && cnt < 16) { op[cnt] = jp[t]; ++cnt; }
  }
}

// ---------------- gather pipeline pieces ------------------------------------
struct PF { float4 f0, f1; float nx, ny, nz; };

DEVFN PF issue_feat(const float* __restrict__ features, const float* __restrict__ xyz,
                    int p, int j, int sub) {
  const int b = p >> 13;
  const float* fr = features + ((size_t)b * Nq + j) * Cq;
  const float* xb = xyz + ((size_t)b * Nq + j) * 3;
  PF r;
  r.f0 = *(const float4*)(fr + sub * 8);
  r.f1 = *(const float4*)(fr + sub * 8 + 4);
  r.nx = xb[0]; r.ny = xb[1]; r.nz = xb[2];
  return r;
}

DEVFN int issue_idx(const int* __restrict__ idx, int p, int lane) {
  return idx[(size_t)p * Kq + (lane >> 2)];
}

DEVFN float3 issue_query(const float* __restrict__ xyz, int p) {
  const float* q = xyz + (size_t)p * 3;  // [B,N,3] flat: p = b*Nq+n
  return make_float3(q[0], q[1], q[2]);
}

// enc row layout: [rel.x rel.y rel.z dist f0..f31] padded to 40 floats.
DEVFN void commit_enc(float* __restrict__ enc, int lane, const PF& pf,
                      float qx, float qy, float qz) {
  const int k = lane >> 2, sub = lane & 3;
  float* er = enc + k * 40;
  *(float4*)(er + 4 + sub * 8) = pf.f0;
  *(float4*)(er + 4 + sub * 8 + 4) = pf.f1;
  if (sub == 0) {
    const float rx = pf.nx - qx, ry = pf.ny - qy, rz = pf.nz - qz;
    const float ss = rx * rx + ry * ry + rz * rz;
    *(float4*)er = make_float4(rx, ry, rz, sqrtf(fmaxf(ss, 1e-12f)));
  }
}

// dot(enc_row[0..35], f16-packed weights) -- 4 accumulators; float(half)*float
// pattern fuses to v_fma_mix (no spill: 18 VGPRs vs 36 for fp32 weights).
DEVFN float dot36h(const float* __restrict__ er, const __half2* __restrict__ wh) {
  float a0 = 0.f, a1 = 0.f, a2 = 0.f, a3 = 0.f;
#pragma unroll
  for (int c4 = 0; c4 < 9; ++c4) {
    const float4 ev = *(const float4*)(er + c4 * 4);
    const __half2 w0 = wh[c4 * 2], w1 = wh[c4 * 2 + 1];
    a0 += ev.x * __low2float(w0);
    a1 += ev.y * __high2float(w0);
    a2 += ev.z * __low2float(w1);
    a3 += ev.w * __high2float(w1);
  }
  return (a0 + a1) + (a2 + a3);
}

// dot(x_row[0..63], f16-packed weights) -- 32 VGPRs vs 64 for fp32.
DEVFN float dot64h(const float* __restrict__ xr, const __half2* __restrict__ sh) {
  float a0 = 0.f, a1 = 0.f, a2 = 0.f, a3 = 0.f;
#pragma unroll
  for (int c4 = 0; c4 < 16; ++c4) {
    const float4 xv = *(const float4*)(xr + c4 * 4);
    const __half2 s0 = sh[c4 * 2], s1 = sh[c4 * 2 + 1];
    a0 += xv.x * __low2float(s0);
    a1 += xv.y * __high2float(s0);
    a2 += xv.z * __low2float(s1);
    a3 += xv.w * __high2float(s1);
  }
  return (a0 + a1) + (a2 + a3);
}

// pipeline open/close macros (body sits between them as ordinary code).
#define GATHER_PROLOGUE                                                      \
  int p = wid;                                                               \
  int jc = issue_idx(idx, p, lane);                                          \
  PF cur = issue_feat(features, xyz, p, jc, lane & 3);                       \
  float3 qc = issue_query(xyz, p);                                           \
  int pn0 = p + nw; if (pn0 >= PTS) pn0 = p;                                 \
  int jn = issue_idx(idx, pn0, lane);                                        \
  float3 qn = issue_query(xyz, pn0);                                         \
  for (; p < PTS; p += nw) {                                                 \
    int pn = p + nw; if (pn >= PTS) pn = p;                                  \
    int pn2 = pn + nw; if (pn2 >= PTS) pn2 = pn;                             \
    PF nxt = issue_feat(features, xyz, pn, jn, lane & 3);                    \
    const int jn2 = issue_idx(idx, pn2, lane);                               \
    const float3 q2 = issue_query(xyz, pn2);                                 \
    commit_enc(enc, lane, cur, qc.x, qc.y, qc.z);                            \
    wavefence();

#define GATHER_EPILOGUE                                                      \
    wavefence();                                                             \
    cur = nxt; qc = qn; qn = q2; jn = jn2;                                   \
  }

// ---------------- encM: M = sum enc^T enc (36x36), v = sum enc --------------
__global__ __launch_bounds__(256) void encM_kernel(const float* __restrict__ xyz,
                                                   const float* __restrict__ features,
                                                   const int* __restrict__ idx,
                                                   float* __restrict__ mstat) {
  __shared__ __align__(16) float encS[4][16 * 40];
  __shared__ float mred[4][36 * 37];
  const int lane = threadIdx.x & 63, wv = threadIdx.x >> 6;
  float* enc = encS[wv];
  const int li = (lane < 36) ? lane : 0;  // clamp: lanes>=36 compute junk, never stored
  float macc[36];
#pragma unroll
  for (int i = 0; i < 36; ++i) macc[i] = 0.f;
  float vacc = 0.f;
  const int wid = blockIdx.x * 4 + wv, nw = gridDim.x * 4;
  GATHER_PROLOGUE
#pragma unroll
    for (int k = 0; k < 16; ++k) {
      const float* er = enc + k * 40;
      const float ei = er[li];
      vacc += ei;
#pragma unroll
      for (int c4 = 0; c4 < 9; ++c4) {
        const float4 ev = *(const float4*)(er + c4 * 4);
        macc[c4 * 4 + 0] += ei * ev.x;
        macc[c4 * 4 + 1] += ei * ev.y;
        macc[c4 * 4 + 2] += ei * ev.z;
        macc[c4 * 4 + 3] += ei * ev.w;
      }
    }
  GATHER_EPILOGUE
  if (lane < 36) {
#pragma unroll
    for (int j = 0; j < 36; ++j) mred[wv][lane * 37 + j] = macc[j];
    mred[wv][lane * 37 + 36] = vacc;
  }
  __syncthreads();
  for (int t = threadIdx.x; t < 36 * 37; t += 256) {
    const float s = mred[0][t] + mred[1][t] + mred[2][t] + mred[3][t];
    atomicAdd(&mstat[t], s);
  }
}

// y-stat finalize from moments (double precision). thread t = br*64+o.
__global__ void y_finalize_kernel(const float* __restrict__ mstat,
                                  const float* __restrict__ wl1,
                                  const float* __restrict__ wl2,
                                  float* __restrict__ bnp) {
  const int t = threadIdx.x;  // 128
  const int br = t >> 6, o = t & 63;
  const float* W = br ? wl2 : wl1;
  double wrow[36];
  for (int c = 0; c < 36; ++c) wrow[c] = (double)W[o * 36 + c];
  double mean = 0.0, ey2 = 0.0;
  for (int i = 0; i < 36; ++i) {
    mean += wrow[i] * (double)mstat[i * 37 + 36];
    double rowacc = 0.0;
    for (int j = 0; j < 36; ++j) rowacc += wrow[j] * (double)mstat[i * 37 + j];
    ey2 += wrow[i] * rowacc;
  }
  const double invR = 1.0 / ROWS;
  mean *= invR; ey2 *= invR;
  const double var = ey2 - mean * mean;
  bnp[DS_Y + br * 64 + o] = (float)mean;
  bnp[DS_Y + 128 + br * 64 + o] = (float)(1.0 / sqrt(var + 1e-5));
}

// ---------------- generic BN stat finalize: mean + rsqrt(var+eps) -----------
__global__ void bn_finalize_kernel(const double* __restrict__ dstat, float* __restrict__ bnp,
                                   int base, double invc) {
  const int t = threadIdx.x;  // 128 threads
  const double m = dstat[base + t] * invc;
  const double v = dstat[base + 128 + t] * invc - m * m;
  bnp[base + t] = (float)m;
  bnp[base + 128 + t] = (float)(1.0 / sqrt(v + 1e-5));
}

// ---------------- passA: x = relu(bn(y)); z = x @ sw1^T; z stats ------------
// f16 weight regs (wh 18 + sh 32 VGPRs) -> no spill at (256,4): 16 waves/CU.
__global__ __launch_bounds__(256, 4) void passA_kernel(const float* __restrict__ xyz,
                                                       const float* __restrict__ features,
                                                       const int* __restrict__ idx,
                                                       const float* __restrict__ wl1,
                                                       const float* __restrict__ wl2,
                                                       const float* __restrict__ s1a,
                                                       const float* __restrict__ s1b,
                                                       const float* __restrict__ bnp,
                                                       double* __restrict__ dstat) {
  const int br = blockIdx.y;
  const float* W = br ? wl2 : wl1;
  const float* S1 = br ? s1b : s1a;
  __shared__ __align__(16) float encS[4][16 * 40];
  __shared__ __align__(16) float xS[4][16 * 64];
  const int lane = threadIdx.x & 63, wv = threadIdx.x >> 6;
  float* enc = encS[wv];
  float* xL = xS[wv];
  __half2 wh[18];
#pragma unroll
  for (int c = 0; c < 18; ++c)
    wh[c] = __floats2half2_rn(W[lane * 36 + 2 * c], W[lane * 36 + 2 * c + 1]);
  __half2 sh[32];
#pragma unroll
  for (int c = 0; c < 32; ++c)
    sh[c] = __floats2half2_rn(S1[lane * 64 + 2 * c], S1[lane * 64 + 2 * c + 1]);
  const float ym = bnp[DS_Y + br * 64 + lane];
  const float ys = bnp[DS_Y + 128 + br * 64 + lane];
  float zs1 = 0.f, zs2 = 0.f;
  const int wid = blockIdx.x * 4 + wv, nw = gridDim.x * 4;
  GATHER_PROLOGUE
#pragma unroll
    for (int k = 0; k < 16; ++k) {
      float xv = (dot36h(enc + k * 40, wh) - ym) * ys;
      xv = xv > 0.f ? xv : 0.f;
      xL[k * 64 + lane] = xv;
    }
    wavefence();
#pragma unroll
    for (int k = 0; k < 16; ++k) {
      const float acc = dot64h(xL + k * 64, sh);
      zs1 += acc; zs2 += acc * acc;
    }
  GATHER_EPILOGUE
  atomicAdd(&dstat[DS_Z + br * 64 + lane], (double)zs1);
  atomicAdd(&dstat[DS_Z + 128 + br * 64 + lane], (double)zs2);
}

// ---------------- passB: full branch -> g = feat @ mw^T raw; g stats --------
__global__ __launch_bounds__(256, 4) void passB_kernel(const float* __restrict__ xyz,
                                                       const float* __restrict__ features,
                                                       const int* __restrict__ idx,
                                                       const float* __restrict__ wl1,
                                                       const float* __restrict__ wl2,
                                                       const float* __restrict__ s1a,
                                                       const float* __restrict__ s1b,
                                                       const float* __restrict__ s2a,
                                                       const float* __restrict__ s2b,
                                                       const float* __restrict__ sba,
                                                       const float* __restrict__ sbb,
                                                       const float* __restrict__ mwa,
                                                       const float* __restrict__ mwb,
                                                       const float* __restrict__ bnp,
                                                       double* __restrict__ dstat,
                                                       float* __restrict__ graw) {
  const int br = blockIdx.y;
  const float* W = br ? wl2 : wl1;
  const float* S1 = br ? s1b : s1a;
  const float* S2 = br ? s2b : s2a;
  const float* SB = br ? sbb : sba;
  const float* MW = br ? mwb : mwa;
  __shared__ __align__(16) __half2 mwl2[64 * 34];  // row stride 34 pairs (68 halves)
  __shared__ __align__(16) float encS[4][16 * 40];
  __shared__ __align__(16) float xS[4][16 * 64];
  __shared__ __align__(16) float featL[4][64];
  for (int t = threadIdx.x; t < 64 * 32; t += 256) {
    const int r = t >> 5, c2 = t & 31;
    mwl2[r * 34 + c2] = __floats2half2_rn(MW[r * 64 + c2 * 2], MW[r * 64 + c2 * 2 + 1]);
  }
  __syncthreads();  // one-time weight staging only
  const int lane = threadIdx.x & 63, wv = threadIdx.x >> 6;
  float* enc = encS[wv];
  float* xL = xS[wv];
  const __half2* mrow = mwl2 + lane * 34;
  __half2 wh[18];
#pragma unroll
  for (int c = 0; c < 18; ++c)
    wh[c] = __floats2half2_rn(W[lane * 36 + 2 * c], W[lane * 36 + 2 * c + 1]);
  __half2 sh[32];
#pragma unroll
  for (int c = 0; c < 32; ++c)
    sh[c] = __floats2half2_rn(S1[lane * 64 + 2 * c], S1[lane * 64 + 2 * c + 1]);
  const float ym = bnp[DS_Y + br * 64 + lane];
  const float ys = bnp[DS_Y + 128 + br * 64 + lane];
  const float zm = bnp[DS_Z + br * 64 + lane];
  const float zs = bnp[DS_Z + 128 + br * 64 + lane];
  const float sw2r = S2[lane];
  const float sb2v = SB[0];
  float gs1 = 0.f, gs2 = 0.f;
  const int wid = blockIdx.x * 4 + wv, nw = gridDim.x * 4;
  GATHER_PROLOGUE
#pragma unroll
    for (int k = 0; k < 16; ++k) {
      float xv = (dot36h(enc + k * 40, wh) - ym) * ys;
      xv = xv > 0.f ? xv : 0.f;
      xL[k * 64 + lane] = xv;
    }
    wavefence();
    float pl[16];
#pragma unroll
    for (int k = 0; k < 16; ++k) {
      float h = (dot64h(xL + k * 64, sh) - zm) * zs;
      h = h > 0.f ? h : 0.f;
      pl[k] = h * sw2r;
    }
#pragma unroll
    for (int off = 1; off < 64; off <<= 1) {
#pragma unroll
      for (int k = 0; k < 16; ++k) pl[k] += __shfl_xor(pl[k], off, 64);
    }
    float mx = -FLT_MAX;
#pragma unroll
    for (int k = 0; k < 16; ++k) { pl[k] += sb2v; mx = fmaxf(mx, pl[k]); }
    float se = 0.f;
#pragma unroll
    for (int k = 0; k < 16; ++k) { pl[k] = expf(pl[k] - mx); se += pl[k]; }
    const float inv = 1.f / se;
    float f = 0.f;
#pragma unroll
    for (int k = 0; k < 16; ++k) f += xL[k * 64 + lane] * (pl[k] * inv);
    featL[wv][lane] = f;
    wavefence();
    const float* featW = &featL[wv][0];
    float g0 = 0.f, g1 = 0.f, g2 = 0.f, g3 = 0.f;
#pragma unroll
    for (int c8 = 0; c8 < 8; ++c8) {
      const float4 fa = *(const float4*)(featW + c8 * 8);
      const float4 fb = *(const float4*)(featW + c8 * 8 + 4);
      const __half2 m0 = mrow[c8 * 4 + 0];
      const __half2 m1 = mrow[c8 * 4 + 1];
      const __half2 m2 = mrow[c8 * 4 + 2];
      const __half2 m3 = mrow[c8 * 4 + 3];
      g0 += fa.x * __low2float(m0); g1 += fa.y * __high2float(m0);
      g2 += fa.z * __low2float(m1); g3 += fa.w * __high2float(m1);
      g0 += fb.x * __low2float(m2); g1 += fb.y * __high2float(m2);
      g2 += fb.z * __low2float(m3); g3 += fb.w * __high2float(m3);
    }
    const float g = (g0 + g1) + (g2 + g3);
    graw[((size_t)br * PTS + p) * 64 + lane] = g;
    gs1 += g; gs2 += g * g;
  GATHER_EPILOGUE
  atomicAdd(&dstat[DS_G + br * 64 + lane], (double)gs1);
  atomicAdd(&dstat[DS_G + 128 + br * 64 + lane], (double)gs2);
}

// ---------------- DRB matmul stage (128x128 per-point matvec + stats) -------
__global__ __launch_bounds__(256) void drb_mm_kernel(const float* __restrict__ in,
                                                     const float* __restrict__ wmat,
                                                     const float* __restrict__ bnp,
                                                     double* __restrict__ dstat,
                                                     float* __restrict__ aggout,
                                                     float* __restrict__ rowout,
                                                     int bpIn, int dsOut, int mode) {
  __shared__ __align__(16) float wlds[128 * 129];
  __shared__ __align__(16) float rowS[4][128];
  for (int t = threadIdx.x; t < 128 * 128; t += 256) wlds[(t >> 7) * 129 + (t & 127)] = wmat[t];
  __syncthreads();  // one-time weight staging only
  const int lane = threadIdx.x & 63, wv = threadIdx.x >> 6;
  const float m0 = bnp[bpIn + lane], s0 = bnp[bpIn + 128 + lane];
  const float m1 = bnp[bpIn + 64 + lane], s1 = bnp[bpIn + 128 + 64 + lane];
  float a1s0 = 0.f, a1s1 = 0.f, a2s0 = 0.f, a2s1 = 0.f;
  const int wid = blockIdx.x * 4 + wv, nw = gridDim.x * 4;
  for (int p = wid; p < PTS; p += nw) {
    float v0, v1;
    if (mode == 0) {  // input = g_raw [2][PTS][64]
      v0 = in[(size_t)p * 64 + lane];
      v1 = in[(size_t)PTS * 64 + (size_t)p * 64 + lane];
    } else {          // input = h1 raw [PTS][128]
      v0 = in[(size_t)p * 128 + lane];
      v1 = in[(size_t)p * 128 + 64 + lane];
    }
    v0 = (v0 - m0) * s0; v0 = v0 > 0.f ? v0 : 0.f;
    v1 = (v1 - m1) * s1; v1 = v1 > 0.f ? v1 : 0.f;
    rowS[wv][lane] = v0;
    rowS[wv][64 + lane] = v1;
    if (aggout) {
      aggout[(size_t)p * 128 + lane] = v0;
      aggout[(size_t)p * 128 + 64 + lane] = v1;
    }
    wavefence();
#pragma unroll
    for (int h = 0; h < 2; ++h) {
      const int o = h * 64 + lane;
      float b0 = 0.f, b1 = 0.f, b2 = 0.f, b3 = 0.f;
#pragma unroll
      for (int c4 = 0; c4 < 32; ++c4) {
        const float4 rv = *(const float4*)(&rowS[wv][c4 * 4]);
        b0 += rv.x * wlds[o * 129 + c4 * 4 + 0];
        b1 += rv.y * wlds[o * 129 + c4 * 4 + 1];
        b2 += rv.z * wlds[o * 129 + c4 * 4 + 2];
        b3 += rv.w * wlds[o * 129 + c4 * 4 + 3];
      }
      const float acc = (b0 + b1) + (b2 + b3);
      rowout[(size_t)p * 128 + o] = acc;
      if (h == 0) { a1s0 += acc; a2s0 += acc * acc; }
      else        { a1s1 += acc; a2s1 += acc * acc; }
    }
    wavefence();
  }
  atomicAdd(&dstat[dsOut + lane], (double)a1s0);
  atomicAdd(&dstat[dsOut + 64 + lane], (double)a1s1);
  atomicAdd(&dstat[dsOut + 128 + lane], (double)a2s0);
  atomicAdd(&dstat[dsOut + 128 + 64 + lane], (double)a2s1);
}

// ---------------- final: out = relu(bn(h2) + agg) ---------------------------
__global__ __launch_bounds__(256) void final_kernel(const float* __restrict__ h2,
                                                    const float* __restrict__ agg,
                                                    const float* __restrict__ bnp,
                                                    float* __restrict__ out) {
  const size_t e = (size_t)blockIdx.x * 256 + threadIdx.x;
  const int ch = (int)(e & 127);
  const float m = bnp[DS_H2 + ch], s = bnp[DS_H2 + 128 + ch];
  float v = (h2[e] - m) * s + agg[e];
  out[e] = v > 0.f ? v : 0.f;
}

extern "C" void kernel_launch(void* const* d_in, const int* in_sizes, int n_in,
                              void* d_out, int out_size, void* d_ws, size_t ws_size,
                              hipStream_t stream) {
  (void)in_sizes; (void)n_in; (void)out_size; (void)ws_size;
  const float* xyz      = (const float*)d_in[0];
  const float* features = (const float*)d_in[1];
  const float* w_lse1   = (const float*)d_in[2];
  const float* w_lse2   = (const float*)d_in[3];
  const float* ap1_sw1  = (const float*)d_in[4];
  const float* ap1_sw2  = (const float*)d_in[5];
  const float* ap1_sb2  = (const float*)d_in[6];
  const float* ap1_mw   = (const float*)d_in[7];
  const float* ap2_sw1  = (const float*)d_in[8];
  const float* ap2_sw2  = (const float*)d_in[9];
  const float* ap2_sb2  = (const float*)d_in[10];
  const float* ap2_mw   = (const float*)d_in[11];
  const float* drb_w1   = (const float*)d_in[12];
  const float* drb_w2   = (const float*)d_in[13];

  char* ws = (char*)d_ws;
  float*  knn_d = (float*)(ws + OFF_A);
  int*    knn_j = (int*)(ws + OFF_B);
  int*    idx   = (int*)(ws + OFF_IDX);
  double* dstat = (double*)(ws + OFF_DST);
  float*  mstat = (float*)(ws + OFF_MST);
  float*  bnp   = (float*)(ws + OFF_BNP);
  float*  graw  = (float*)(ws + OFF_A);   // reuse after knn done
  float*  agg   = (float*)(ws + OFF_B);   // reuse after knn done
  float*  h1    = (float*)(ws + OFF_H1);
  float*  h2    = (float*)(ws + OFF_H2);
  float*  out   = (float*)d_out;

  // zero dstat (1280 doubles) + mstat (36*37 floats, contiguous after)
  (void)hipMemsetAsync(dstat, 0, 1280 * sizeof(double) + 36 * 37 * sizeof(float), stream);

  knn_chunk_kernel<<<dim3(Nq / 256, CH, Bq), 256, 0, stream>>>(xyz, knn_d, knn_j);
  knn_merge_kernel<<<dim3(PTS / 256), 256, 0, stream>>>(knn_d, knn_j, idx);

  encM_kernel<<<dim3(1280), 256, 0, stream>>>(xyz, features, idx, mstat);
  y_finalize_kernel<<<1, 128, 0, stream>>>(mstat, w_lse1, w_lse2, bnp);

  passA_kernel<<<dim3(512, 2), 256, 0, stream>>>(xyz, features, idx, w_lse1, w_lse2,
                                                 ap1_sw1, ap2_sw1, bnp, dstat);
  bn_finalize_kernel<<<1, 128, 0, stream>>>(dstat, bnp, DS_Z, 1.0 / ROWS);

  passB_kernel<<<dim3(512, 2), 256, 0, stream>>>(xyz, features, idx, w_lse1, w_lse2,
                                                 ap1_sw1, ap2_sw1, ap1_sw2, ap2_sw2,
                                                 ap1_sb2, ap2_sb2, ap1_mw, ap2_mw,
                                                 bnp, dstat, graw);
  bn_finalize_kernel<<<1, 128, 0, stream>>>(dstat, bnp, DS_G, 1.0 / PTS);

  drb_mm_kernel<<<dim3(512), 256, 0, stream>>>(graw, drb_w1, bnp, dstat, agg, h1,
                                               DS_G, DS_H1, 0);
  bn_finalize_kernel<<<1, 128, 0, stream>>>(dstat, bnp, DS_H1, 1.0 / PTS);

  drb_mm_kernel<<<dim3(512), 256, 0, stream>>>(h1, drb_w2, bnp, dstat, nullptr, h2,
                                               DS_H1, DS_H2, 1);
  bn_finalize_kernel<<<1, 128, 0, stream>>>(dstat, bnp, DS_H2, 1.0 / PTS);

  final_kernel<<<dim3(PTS * 128 / 256), 256, 0, stream>>>(h2, agg, bnp, out);
}